// Round 9
// baseline (1116.436 us; speedup 1.0000x reference)
//
#include <hip/hip_runtime.h>
#include <stdint.h>

typedef unsigned short ushort_t;
typedef unsigned int uint_t;
typedef __bf16 bf16x8 __attribute__((ext_vector_type(8)));
typedef float f32x4 __attribute__((ext_vector_type(4)));

#define SCALE_CONV 0.014731391f   /* 1/sqrt(512*9) */
#define SCALE_RGB  0.044194174f   /* 1/sqrt(512)   */
#define SQRT2_F    1.41421356237f

// ---------------------------------------------------------------- helpers
__device__ __forceinline__ ushort_t f2bf(float v) {
  union { float f; uint_t u; } c; c.f = v;
  uint_t r = c.u + 0x7fffu + ((c.u >> 16) & 1u);   // RNE
  return (ushort_t)(r >> 16);
}
__device__ __forceinline__ float bf2f(ushort_t u) {
  union { uint_t u; float f; } c; c.u = ((uint_t)u) << 16;
  return c.f;
}

// ------------------------------------------------- prep (merged): x->xpad1 and w1/w2->wt/wsqT
__global__ __launch_bounds__(256) void prep_all(
    const float* __restrict__ x, const float* __restrict__ s1,
    ushort_t* __restrict__ xpad,
    const float* __restrict__ w1, const float* __restrict__ w2,
    ushort_t* __restrict__ wt1, ushort_t* __restrict__ wt2,
    float* __restrict__ wsqT1, float* __restrict__ wsqT2) {
  if (blockIdx.x < 256) {
    __shared__ ushort_t t[32 * 520];
    const int b  = blockIdx.x >> 5;
    const int j1 = blockIdx.x & 31;
    for (int idx = threadIdx.x; idx < 512 * 32; idx += 256) {
      int ci = idx >> 5, j2 = idx & 31;
      float v = x[(size_t)(b * 512 + ci) * 1024 + j1 * 32 + j2];
      v *= s1[b * 512 + ci] * SCALE_CONV;
      t[j2 * 520 + ci] = f2bf(v);
    }
    __syncthreads();
    for (int idx = threadIdx.x; idx < 32 * 512; idx += 256) {
      int j2 = idx >> 9, ci = idx & 511;
      xpad[((size_t)(b * 34 + j1 + 1) * 34 + (j2 + 1)) * 512 + ci] = t[j2 * 520 + ci];
    }
    return;
  }
  int t = (blockIdx.x - 256) * 256 + threadIdx.x;   // 2*512*512
  const float* w  = (t < 262144) ? w1 : w2;
  ushort_t*   wt  = (t < 262144) ? wt1 : wt2;
  float*      wq  = (t < 262144) ? wsqT1 : wsqT2;
  int tt = t & 262143;
  int ci = tt & 511, co = tt >> 9;
  const float* wp = w + (size_t)(co * 512 + ci) * 9;
  float sq = 0.f;
#pragma unroll
  for (int u = 0; u < 9; ++u) {
    float v = wp[u];
    sq += v * v;
    wt[((size_t)u * 512 + co) * 512 + ci] = f2bf(v);
  }
  wq[ci * 512 + co] = sq;
}

// ------------------------------------------------- demod (parallel): grid (8 cog, 8 b, 2 which)
__global__ __launch_bounds__(256) void demod3(
    const float* __restrict__ wsqT1, const float* __restrict__ s1, float* __restrict__ d1,
    const float* __restrict__ wsqT2, const float* __restrict__ s2, float* __restrict__ d2) {
  const float* wq = blockIdx.z ? wsqT2 : wsqT1;
  const float* s  = blockIdx.z ? s2 : s1;
  float*       d  = blockIdx.z ? d2 : d1;
  const int b   = blockIdx.y;
  const int co  = blockIdx.x * 64 + (threadIdx.x & 63);
  const int cig = threadIdx.x >> 6;
  __shared__ float ssq[512];
  __shared__ float red[4][64];
  for (int i = threadIdx.x; i < 512; i += 256) {
    float v = s[b * 512 + i];
    ssq[i] = v * v;
  }
  __syncthreads();
  float a = 0.f;
#pragma unroll 4
  for (int ci = cig * 128; ci < cig * 128 + 128; ++ci)
    a += wq[ci * 512 + co] * ssq[ci];
  red[cig][threadIdx.x & 63] = a;
  __syncthreads();
  if (cig == 0) {
    int l = threadIdx.x & 63;
    float tot = red[0][l] + red[1][l] + red[2][l] + red[3][l];
    d[b * 512 + co] = rsqrtf(tot * (1.f / 4608.f) + 1e-8f);
  }
}

// ------------------------------------------------- zero pad borders + rgbpart
__global__ __launch_bounds__(256) void border_zero(
    ushort_t* __restrict__ xpad, ushort_t* __restrict__ ypad, ushort_t* __restrict__ opad,
    float* __restrict__ rgbpart) {
  const int z = blockIdx.z;
  if (z == 3) {
    int i = (blockIdx.y * 66 + blockIdx.x) * 256 + threadIdx.x;
    if (i < 24576) {                       // 3*32768 floats / 4 per uint4
      uint4 z4 = {0, 0, 0, 0};
      *(uint4*)(rgbpart + i * 4) = z4;
    }
    return;
  }
  ushort_t* p = (z == 0) ? xpad : (z == 1 ? ypad : opad);
  const int W = (z == 0) ? 34 : (z == 1 ? 67 : 66);
  const int nb = 4 * W - 4;
  const int t = blockIdx.x * 256 + threadIdx.x;
  const int pix = t >> 6, ch = (t & 63) * 8;
  if (pix >= nb) return;
  const int b = blockIdx.y;
  int y, x;
  if (pix < W)          { y = 0;     x = pix; }
  else if (pix < 2 * W) { y = W - 1; x = pix - W; }
  else { int q = pix - 2 * W; y = 1 + (q >> 1); x = (q & 1) ? W - 1 : 0; }
  uint4 z4 = {0, 0, 0, 0};
  *(uint4*)(p + ((size_t)(b * W + y) * W + x) * 512 + ch) = z4;
}

// ------------------------------------------------- conv1 phase tap tables (convT stride-2, k=3)
__constant__ int           c_ph_off[4]  = {0, 4, 6, 8};
__constant__ int           c_ph_ntap[4] = {4, 2, 2, 1};
__constant__ unsigned char c_tap_u1[9]  = {0,0,1,1, 0,1, 1,1, 1};
__constant__ unsigned char c_tap_u2[9]  = {0,1,0,1, 1,1, 0,1, 1};
__constant__ unsigned char c_tap_pl[9]  = {8,6,2,0, 7,1, 5,3, 4};

// ================================================= register-staged GEMM conv core
// Single 32 KB LDS buffer, BK=64. Per iter: compute k from LDS; lgkm-barrier; ds_write k+1
// from regs (their global loads issued a full iteration earlier -> vmcnt satisfied);
// issue global loads for k+2; lgkm-only raw s_barrier (k+2 loads stay in flight).
// LDS layout identical to R7's global_load_lds scatter: lane writes 16B at
// wv*4096 + t*1024 + lane*16 (R8 BUG was omitting the lane*16 term).
template <int MODE>
__device__ __forceinline__ void gemm_core(
    int mtile, int ntile, int a,
    const ushort_t* __restrict__ inp, const ushort_t* __restrict__ wt,
    f32x4 (&acc)[4][4], int (&offA)[4], int (&offB)[4],
    ushort_t* ldsA, ushort_t* ldsB) {
  const int tid  = threadIdx.x;
  const int lane = tid & 63;
  const int wv   = tid >> 6;

  const int phoff = (MODE == 0) ? c_ph_off[a] : 0;
  const int nk    = (MODE == 0) ? c_ph_ntap[a] * 8 : 72;

  const int cl = ((lane & 7) - (lane >> 3)) & 7;
  const char* pA[4];
  const char* pB[4];
#pragma unroll
  for (int t = 0; t < 4; ++t) {
    int row = wv * 32 + t * 8 + (lane >> 3);
    int m   = mtile * 128 + row;
    size_t pix;
    if (MODE == 0) {
      if (m > 8711) m = 8711;
      int b = m / 1089, rr = m % 1089;
      int p1 = rr / 33, p2 = rr % 33;
      pix = ((size_t)(b * 34 + p1) * 34 + p2) * 512;
    } else {
      int b = m >> 12, o1 = (m >> 6) & 63, o2 = m & 63;
      pix = ((size_t)(b * 66 + o1 + 1) * 66 + (o2 + 1)) * 512;
    }
    pA[t] = (const char*)inp + pix * 2 + cl * 16;
    int n = ntile * 128 + row;
    pB[t] = (const char*)wt + (size_t)n * 1024 + cl * 16;
  }
  // per-lane LDS destinations (ushort units): byte = wv*4096 + t*1024 + lane*16
  ushort_t* dstA[4];
  ushort_t* dstB[4];
#pragma unroll
  for (int t = 0; t < 4; ++t) {
    dstA[t] = ldsA + wv * 2048 + t * 512 + lane * 8;
    dstB[t] = ldsB + wv * 2048 + t * 512 + lane * 8;
  }

  uint4 rA[4], rB[4];
  auto loadRegs = [&](int kn) {
    int tap = kn >> 3, kc = kn & 7;
    int aoff, boff;
    if (MODE == 0) {
      int e = phoff + tap;
      aoff = ((int)c_tap_u1[e] * 34 + (int)c_tap_u2[e]) * 1024 + kc * 128;
      boff = (int)c_tap_pl[e] * 524288 + kc * 128;
    } else {
      int ty = (tap * 86) >> 8;           // tap/3
      int tx = tap - ty * 3;
      aoff = ((ty - 1) * 66 + (tx - 1)) * 1024 + kc * 128;
      boff = tap * 524288 + kc * 128;
    }
#pragma unroll
    for (int t = 0; t < 4; ++t) {
      rA[t] = *(const uint4*)(pA[t] + aoff);
      rB[t] = *(const uint4*)(pB[t] + boff);
    }
  };
  auto writeLds = [&]() {
#pragma unroll
    for (int t = 0; t < 4; ++t) {
      *(uint4*)dstA[t] = rA[t];
      *(uint4*)dstB[t] = rB[t];
    }
  };

  loadRegs(0);
  writeLds();                      // compiler inserts vmcnt wait (reg dep)
  if (nk > 1) loadRegs(1);
  asm volatile("s_waitcnt lgkmcnt(0)\ns_barrier" ::: "memory");

#pragma unroll 1
  for (int k = 0; k < nk; ++k) {
    // compute tile k from LDS
#pragma unroll
    for (int kk = 0; kk < 2; ++kk) {
      const int kx = kk << 5;
      bf16x8 af[4], bg[4];
#pragma unroll
      for (int i = 0; i < 4; ++i) af[i] = *reinterpret_cast<const bf16x8*>(ldsA + (offA[i] ^ kx));
#pragma unroll
      for (int j = 0; j < 4; ++j) bg[j] = *reinterpret_cast<const bf16x8*>(ldsB + (offB[j] ^ kx));
#pragma unroll
      for (int i = 0; i < 4; ++i)
#pragma unroll
        for (int j = 0; j < 4; ++j)
          acc[i][j] = __builtin_amdgcn_mfma_f32_16x16x32_bf16(af[i], bg[j], acc[i][j], 0, 0, 0);
    }
    if (k + 1 < nk) {
      asm volatile("s_waitcnt lgkmcnt(0)\ns_barrier" ::: "memory");  // all waves done reading
      writeLds();                                // k+1 tile (vmcnt auto-satisfied)
      if (k + 2 < nk) loadRegs(k + 2);           // stays in flight across barrier
      asm volatile("s_waitcnt lgkmcnt(0)\ns_barrier" ::: "memory");  // writes visible
    }
  }
}

// ------------------------------------------------- conv1: unfused convT phase GEMM, XCD-swizzled
__global__ __launch_bounds__(256, 3) void gemm_conv1(
    const ushort_t* __restrict__ inp, const ushort_t* __restrict__ wt,
    const float* __restrict__ dmod, ushort_t* __restrict__ outp) {
  const int g = blockIdx.x;
  const int mtile = ((g >> 7) << 3) | (g & 7);   // 0..71
  if (mtile >= 69) return;
  const int sub   = (g >> 3) & 15;
  const int a     = sub >> 2;
  const int ntile = sub & 3;
  const int a1 = a >> 1, a2 = a & 1;

  __shared__ ushort_t ldsA[128 * 64];
  __shared__ ushort_t ldsB[128 * 64];

  const int lane = threadIdx.x & 63;
  const int wv   = threadIdx.x >> 6;
  const int wm   = wv & 1;
  const int wn   = wv >> 1;
  const int l16  = lane & 15;
  const int quad = lane >> 4;

  int offA[4], offB[4];
#pragma unroll
  for (int i = 0; i < 4; ++i) {
    int r  = wm * 64 + i * 16 + l16;
    int rn = wn * 64 + i * 16 + l16;
    offA[i] = r  * 64 + (((quad + r)  & 7) << 3);
    offB[i] = rn * 64 + (((quad + rn) & 7) << 3);
  }
  f32x4 acc[4][4];
#pragma unroll
  for (int i = 0; i < 4; ++i)
#pragma unroll
    for (int j = 0; j < 4; ++j) acc[i][j] = (f32x4){0.f, 0.f, 0.f, 0.f};

  gemm_core<0>(mtile, ntile, a, inp, wt, acc, offA, offB, ldsA, ldsB);

  int co_[4];
#pragma unroll
  for (int j = 0; j < 4; ++j) co_[j] = ntile * 128 + wn * 64 + j * 16 + l16;
#pragma unroll
  for (int i = 0; i < 4; ++i) {
#pragma unroll
    for (int r = 0; r < 4; ++r) {
      int m = mtile * 128 + wm * 64 + i * 16 + quad * 4 + r;
      if (m < 8712) {
        int b = m / 1089, rr = m % 1089;
        int p1 = rr / 33, p2 = rr % 33;
        if ((a1 == 0 || p1 < 32) && (a2 == 0 || p2 < 32)) {
          int o1 = 2 * p1 + a1, o2 = 2 * p2 + a2;
          size_t ob = ((size_t)(b * 67 + o1 + 1) * 67 + (o2 + 1)) * 512;
#pragma unroll
          for (int j = 0; j < 4; ++j)
            outp[ob + co_[j]] = f2bf(acc[i][j][r] * dmod[b * 512 + co_[j]]);
        }
      }
    }
  }
}

// ------------------------------------------------- conv2 + fused ToRGB, XCD-swizzled
__global__ __launch_bounds__(256, 3) void gemm_conv2(
    const ushort_t* __restrict__ inp, const ushort_t* __restrict__ wt,
    const float* __restrict__ dmod, const float* __restrict__ noise,
    const float* __restrict__ nw, const float* __restrict__ bias,
    const float* __restrict__ srgb, const float* __restrict__ wrgb,
    float* __restrict__ rgbpart) {
  const int g = blockIdx.x;
  const int mtile = ((g >> 5) << 3) | (g & 7);
  const int ntile = (g >> 3) & 3;

  __shared__ ushort_t ldsA[128 * 64];
  __shared__ ushort_t ldsB[128 * 64];

  const int lane = threadIdx.x & 63;
  const int wv   = threadIdx.x >> 6;
  const int wm   = wv & 1;
  const int wn   = wv >> 1;
  const int l16  = lane & 15;
  const int quad = lane >> 4;

  int offA[4], offB[4];
#pragma unroll
  for (int i = 0; i < 4; ++i) {
    int r  = wm * 64 + i * 16 + l16;
    int rn = wn * 64 + i * 16 + l16;
    offA[i] = r  * 64 + (((quad + r)  & 7) << 3);
    offB[i] = rn * 64 + (((quad + rn) & 7) << 3);
  }
  f32x4 acc[4][4];
#pragma unroll
  for (int i = 0; i < 4; ++i)
#pragma unroll
    for (int j = 0; j < 4; ++j) acc[i][j] = (f32x4){0.f, 0.f, 0.f, 0.f};

  gemm_core<1>(mtile, ntile, 0, inp, wt, acc, offA, offB, ldsA, ldsB);

  // ---- epilogue: demod + noise + bias + lrelu*sqrt2 + srgb scale, then RGB projection
  const int b = mtile >> 5;
  int co_[4];
#pragma unroll
  for (int j = 0; j < 4; ++j) co_[j] = ntile * 128 + wn * 64 + j * 16 + l16;
  const float nwv = nw[0];
  float dj_[4], sj_[4], bj_[4], wr[3][4];
#pragma unroll
  for (int j = 0; j < 4; ++j) {
    dj_[j] = dmod[b * 512 + co_[j]];
    sj_[j] = srgb[b * 512 + co_[j]] * SCALE_RGB;
    bj_[j] = bias[co_[j]];
#pragma unroll
    for (int c = 0; c < 3; ++c) wr[c][j] = wrgb[c * 512 + co_[j]];
  }
#pragma unroll
  for (int i = 0; i < 4; ++i) {
#pragma unroll
    for (int r = 0; r < 4; ++r) {
      int m = mtile * 128 + wm * 64 + i * 16 + quad * 4 + r;
      int o1 = (m >> 6) & 63, o2 = m & 63;
      float nz = nwv * noise[(b << 12) + (o1 << 6) + o2];
      float vv[4];
#pragma unroll
      for (int j = 0; j < 4; ++j) {
        float v = acc[i][j][r] * dj_[j] + nz + bj_[j];
        v = (v >= 0.f ? v : 0.2f * v) * SQRT2_F;
        vv[j] = v * sj_[j];
      }
#pragma unroll
      for (int c = 0; c < 3; ++c) {
        float s = vv[0] * wr[c][0] + vv[1] * wr[c][1] + vv[2] * wr[c][2] + vv[3] * wr[c][3];
        s += __shfl_xor(s, 1);
        s += __shfl_xor(s, 2);
        s += __shfl_xor(s, 4);
        s += __shfl_xor(s, 8);
        if (l16 == 0) atomicAdd(&rgbpart[c * 32768 + m], s);
      }
    }
  }
}

// ------------------------------------------------- blur(4-tap separable) + noise + bias + lrelu + s2-scale
__global__ __launch_bounds__(256) void blur_noise_act(
    const ushort_t* __restrict__ y1pad, const float* __restrict__ noise,
    const float* __restrict__ nw, const float* __restrict__ bias,
    const float* __restrict__ s2, ushort_t* __restrict__ out1pad) {
  const int cg  = threadIdx.x & 63;                       // channel octet
  const int pg  = blockIdx.x * 4 + (threadIdx.x >> 6);    // 0..4095
  const int b   = pg >> 9;
  const int q1  = (pg >> 3) & 63;
  const int q2g = (pg & 7) * 8;                           // 8 consecutive output cols
  const float cw[4] = {0.25f, 0.75f, 0.75f, 0.25f};

  float acc[8][8];
#pragma unroll
  for (int j = 0; j < 8; ++j)
#pragma unroll
    for (int e = 0; e < 8; ++e) acc[j][e] = 0.f;

#pragma unroll
  for (int t2 = 0; t2 < 11; ++t2) {
    int cc = q2g + t2;
    float vt[8];
#pragma unroll
    for (int e = 0; e < 8; ++e) vt[e] = 0.f;
#pragma unroll
    for (int t1 = 0; t1 < 4; ++t1) {
      const ushort_t* p = y1pad + ((size_t)(b * 67 + q1 + t1) * 67 + cc) * 512 + cg * 8;
      ushort_t v[8];
      *(uint4*)v = *(const uint4*)p;
#pragma unroll
      for (int e = 0; e < 8; ++e) vt[e] += cw[t1] * bf2f(v[e]);
    }
#pragma unroll
    for (int j = 0; j < 8; ++j) {
      int t = t2 - j;
      if (t >= 0 && t < 4) {
#pragma unroll
        for (int e = 0; e < 8; ++e) acc[j][e] += cw[t] * vt[e];
      }
    }
  }

  const float nwv = nw[0];
  float bj[8], sj[8];
#pragma unroll
  for (int e = 0; e < 8; ++e) {
    bj[e] = bias[cg * 8 + e];
    sj[e] = s2[b * 512 + cg * 8 + e] * SCALE_CONV;
  }
#pragma unroll
  for (int j = 0; j < 8; ++j) {
    int q2 = q2g + j;
    float nz = nwv * noise[(b << 12) + (q1 << 6) + q2];
    ushort_t o[8];
#pragma unroll
    for (int e = 0; e < 8; ++e) {
      float v = acc[j][e] + nz + bj[e];
      v = (v >= 0.f ? v : 0.2f * v) * SQRT2_F * sj[e];
      o[e] = f2bf(v);
    }
    *(uint4*)(out1pad + ((size_t)(b * 66 + q1 + 1) * 66 + (q2 + 1)) * 512 + cg * 8) = *(uint4*)o;
  }
}

// ------------------------------------------------- final: rgbpart + bias + skip upfirdn(up=2) -> out
__global__ __launch_bounds__(256) void rgb_finish(
    const float* __restrict__ rgbpart, const float* __restrict__ brgb,
    const float* __restrict__ skip, float* __restrict__ out) {
  const int t = blockIdx.x * 256 + threadIdx.x;   // 3*32768
  if (t >= 98304) return;
  const int m = t & 32767, c = t >> 15;
  const int b = m >> 12, o1 = (m >> 6) & 63, o2 = m & 63;
  int P1 = o1 >> 1, P2 = o2 >> 1;
  int jy0, jy1, jx0, jx1;
  float wy0, wy1, wx0, wx1;
  if ((o1 & 1) == 0) { jy0 = P1 - 1; wy0 = .25f; jy1 = P1;     wy1 = .75f; }
  else               { jy0 = P1;     wy0 = .75f; jy1 = P1 + 1; wy1 = .25f; }
  if ((o2 & 1) == 0) { jx0 = P2 - 1; wx0 = .25f; jx1 = P2;     wx1 = .75f; }
  else               { jx0 = P2;     wx0 = .75f; jx1 = P2 + 1; wx1 = .25f; }
  const float* sp = skip + (size_t)(b * 3 + c) * 1024;
  float sv = 0.f;
  if (jy0 >= 0 && jy0 < 32) {
    if (jx0 >= 0 && jx0 < 32) sv += wy0 * wx0 * sp[jy0 * 32 + jx0];
    if (jx1 >= 0 && jx1 < 32) sv += wy0 * wx1 * sp[jy0 * 32 + jx1];
  }
  if (jy1 >= 0 && jy1 < 32) {
    if (jx0 >= 0 && jx0 < 32) sv += wy1 * wx0 * sp[jy1 * 32 + jx0];
    if (jx1 >= 0 && jx1 < 32) sv += wy1 * wx1 * sp[jy1 * 32 + jx1];
  }
  out[((size_t)(b * 3 + c) << 12) + (o1 << 6) + o2] = rgbpart[c * 32768 + m] + brgb[c] + sv;
}

// ------------------------------------------------- launch
extern "C" void kernel_launch(void* const* d_in, const int* in_sizes, int n_in,
                              void* d_out, int out_size, void* d_ws, size_t ws_size,
                              hipStream_t stream) {
  const float* x    = (const float*)d_in[0];
  const float* skip = (const float*)d_in[1];
  const float* w1   = (const float*)d_in[2];
  const float* b1   = (const float*)d_in[3];
  const float* s1   = (const float*)d_in[4];
  const float* nw1  = (const float*)d_in[5];
  const float* n1   = (const float*)d_in[6];
  const float* w2   = (const float*)d_in[7];
  const float* b2   = (const float*)d_in[8];
  const float* s2   = (const float*)d_in[9];
  const float* nw2  = (const float*)d_in[10];
  const float* n2   = (const float*)d_in[11];
  const float* wrgb = (const float*)d_in[12];
  const float* brgb = (const float*)d_in[13];
  const float* srgb = (const float*)d_in[14];

  char* ws = (char*)d_ws;
  const size_t XPAD_B  = (size_t)8 * 34 * 34 * 512 * 2;   //  9,469,952
  const size_t Y1PAD_B = (size_t)8 * 67 * 67 * 512 * 2;   // 36,773,888
  const size_t OUT1_B  = (size_t)8 * 66 * 66 * 512 * 2;   // 35,684,352
  const size_t WT_B    = (size_t)9 * 512 * 512 * 2;       //  4,718,592
  size_t off = 0;
  ushort_t* xpad1   = (ushort_t*)(ws + off); off += XPAD_B;
  ushort_t* y1pad   = (ushort_t*)(ws + off); off += Y1PAD_B;
  ushort_t* out1pad = (ushort_t*)(ws + off); off += OUT1_B;
  ushort_t* wt1     = (ushort_t*)(ws + off); off += WT_B;
  ushort_t* wt2     = (ushort_t*)(ws + off); off += WT_B;
  float*    d1      = (float*)(ws + off);    off += 8 * 512 * 4;
  float*    d2      = (float*)(ws + off);    off += 8 * 512 * 4;
  float*    rgbpart = (float*)(ws + off);    off += 3 * 32768 * 4;
  // wsqT1/2 alias y1pad (consumed by demod3 before border_zero/gemm touch y1pad)
  float*    wsqT1  = (float*)y1pad;
  float*    wsqT2  = wsqT1 + 512 * 512;

  prep_all<<<2304, 256, 0, stream>>>(x, s1, xpad1, w1, w2, wt1, wt2, wsqT1, wsqT2);
  demod3<<<dim3(8, 8, 2), 256, 0, stream>>>(wsqT1, s1, d1, wsqT2, s2, d2);
  border_zero<<<dim3(66, 8, 4), 256, 0, stream>>>(xpad1, y1pad, out1pad, rgbpart);

  // conv1: unfused convT (4 phases, 9 taps total), XCD-swizzled, reg-staged -> y1pad
  gemm_conv1<<<1152, 256, 0, stream>>>(xpad1, wt1, d1, y1pad);
  // blur + noise + bias + lrelu + s2-scale -> out1pad
  blur_noise_act<<<1024, 256, 0, stream>>>(y1pad, n1, nw1, b1, s2, out1pad);
  // conv2 (XCD-swizzled, reg-staged) + fused ToRGB partial reduction -> rgbpart
  gemm_conv2<<<1024, 256, 0, stream>>>(
      out1pad, wt2, d2, n2, nw2, b2, srgb, wrgb, rgbpart);
  // final: rgb bias + skip upsample
  rgb_finish<<<384, 256, 0, stream>>>(rgbpart, brgb, skip, (float*)d_out);
}

// Round 10
// 410.705 us; speedup vs baseline: 2.7183x; 2.7183x over previous
//
#include <hip/hip_runtime.h>
#include <stdint.h>

typedef unsigned short ushort_t;
typedef unsigned int uint_t;
typedef __bf16 bf16x8 __attribute__((ext_vector_type(8)));
typedef float f32x4 __attribute__((ext_vector_type(4)));

#define GLOBAL_AS __attribute__((address_space(1)))
#define LDS_AS    __attribute__((address_space(3)))

#define SCALE_CONV 0.014731391f   /* 1/sqrt(512*9) */
#define SCALE_RGB  0.044194174f   /* 1/sqrt(512)   */
#define SQRT2_F    1.41421356237f

// ---------------------------------------------------------------- helpers
__device__ __forceinline__ void async_cp16(const void* g, void* l) {
  __builtin_amdgcn_global_load_lds((const GLOBAL_AS uint_t*)g,
                                   (LDS_AS uint_t*)l, 16, 0, 0);
}
__device__ __forceinline__ ushort_t f2bf(float v) {
  union { float f; uint_t u; } c; c.f = v;
  uint_t r = c.u + 0x7fffu + ((c.u >> 16) & 1u);   // RNE
  return (ushort_t)(r >> 16);
}
__device__ __forceinline__ float bf2f(ushort_t u) {
  union { uint_t u; float f; } c; c.u = ((uint_t)u) << 16;
  return c.f;
}

// ------------------------------------------------- prep (merged): x->xpad1 and w1/w2->wt/wsqT
__global__ __launch_bounds__(256) void prep_all(
    const float* __restrict__ x, const float* __restrict__ s1,
    ushort_t* __restrict__ xpad,
    const float* __restrict__ w1, const float* __restrict__ w2,
    ushort_t* __restrict__ wt1, ushort_t* __restrict__ wt2,
    float* __restrict__ wsqT1, float* __restrict__ wsqT2) {
  if (blockIdx.x < 256) {
    __shared__ ushort_t t[32 * 520];
    const int b  = blockIdx.x >> 5;
    const int j1 = blockIdx.x & 31;
    for (int idx = threadIdx.x; idx < 512 * 32; idx += 256) {
      int ci = idx >> 5, j2 = idx & 31;
      float v = x[(size_t)(b * 512 + ci) * 1024 + j1 * 32 + j2];
      v *= s1[b * 512 + ci] * SCALE_CONV;
      t[j2 * 520 + ci] = f2bf(v);
    }
    __syncthreads();
    for (int idx = threadIdx.x; idx < 32 * 512; idx += 256) {
      int j2 = idx >> 9, ci = idx & 511;
      xpad[((size_t)(b * 34 + j1 + 1) * 34 + (j2 + 1)) * 512 + ci] = t[j2 * 520 + ci];
    }
    return;
  }
  int t = (blockIdx.x - 256) * 256 + threadIdx.x;   // 2*512*512
  const float* w  = (t < 262144) ? w1 : w2;
  ushort_t*   wt  = (t < 262144) ? wt1 : wt2;
  float*      wq  = (t < 262144) ? wsqT1 : wsqT2;
  int tt = t & 262143;
  int ci = tt & 511, co = tt >> 9;
  const float* wp = w + (size_t)(co * 512 + ci) * 9;
  float sq = 0.f;
#pragma unroll
  for (int u = 0; u < 9; ++u) {
    float v = wp[u];
    sq += v * v;
    wt[((size_t)u * 512 + co) * 512 + ci] = f2bf(v);
  }
  wq[ci * 512 + co] = sq;
}

// ------------------------------------------------- demod (parallel): grid (8 cog, 8 b, 2 which)
__global__ __launch_bounds__(256) void demod3(
    const float* __restrict__ wsqT1, const float* __restrict__ s1, float* __restrict__ d1,
    const float* __restrict__ wsqT2, const float* __restrict__ s2, float* __restrict__ d2) {
  const float* wq = blockIdx.z ? wsqT2 : wsqT1;
  const float* s  = blockIdx.z ? s2 : s1;
  float*       d  = blockIdx.z ? d2 : d1;
  const int b   = blockIdx.y;
  const int co  = blockIdx.x * 64 + (threadIdx.x & 63);
  const int cig = threadIdx.x >> 6;
  __shared__ float ssq[512];
  __shared__ float red[4][64];
  for (int i = threadIdx.x; i < 512; i += 256) {
    float v = s[b * 512 + i];
    ssq[i] = v * v;
  }
  __syncthreads();
  float a = 0.f;
#pragma unroll 4
  for (int ci = cig * 128; ci < cig * 128 + 128; ++ci)
    a += wq[ci * 512 + co] * ssq[ci];
  red[cig][threadIdx.x & 63] = a;
  __syncthreads();
  if (cig == 0) {
    int l = threadIdx.x & 63;
    float tot = red[0][l] + red[1][l] + red[2][l] + red[3][l];
    d[b * 512 + co] = rsqrtf(tot * (1.f / 4608.f) + 1e-8f);
  }
}

// ------------------------------------------------- zero pad borders + rgbpart
__global__ __launch_bounds__(256) void border_zero(
    ushort_t* __restrict__ xpad, ushort_t* __restrict__ ypad, ushort_t* __restrict__ opad,
    float* __restrict__ rgbpart) {
  const int z = blockIdx.z;
  if (z == 3) {
    int i = (blockIdx.y * 66 + blockIdx.x) * 256 + threadIdx.x;
    if (i < 24576) {                       // 3*32768 floats / 4 per uint4
      uint4 z4 = {0, 0, 0, 0};
      *(uint4*)(rgbpart + i * 4) = z4;
    }
    return;
  }
  ushort_t* p = (z == 0) ? xpad : (z == 1 ? ypad : opad);
  const int W = (z == 0) ? 34 : (z == 1 ? 67 : 66);
  const int nb = 4 * W - 4;
  const int t = blockIdx.x * 256 + threadIdx.x;
  const int pix = t >> 6, ch = (t & 63) * 8;
  if (pix >= nb) return;
  const int b = blockIdx.y;
  int y, x;
  if (pix < W)          { y = 0;     x = pix; }
  else if (pix < 2 * W) { y = W - 1; x = pix - W; }
  else { int q = pix - 2 * W; y = 1 + (q >> 1); x = (q & 1) ? W - 1 : 0; }
  uint4 z4 = {0, 0, 0, 0};
  *(uint4*)(p + ((size_t)(b * W + y) * W + x) * 512 + ch) = z4;
}

// ------------------------------------------------- conv1 phase tap tables (convT stride-2, k=3)
__constant__ int           c_ph_off[4]  = {0, 4, 6, 8};
__constant__ int           c_ph_ntap[4] = {4, 2, 2, 1};
__constant__ unsigned char c_tap_u1[9]  = {0,0,1,1, 0,1, 1,1, 1};
__constant__ unsigned char c_tap_u2[9]  = {0,1,0,1, 1,1, 0,1, 1};
__constant__ unsigned char c_tap_pl[9]  = {8,6,2,0, 7,1, 5,3, 4};

// ================================================= GEMM core, single 32 KB buffer, BK=64.
// Reordered pipeline: per iter -> ds_read ALL frags of tile k; __syncthreads (all waves done
// reading LDS); issue global_load_lds for k+1 (latency covered by the 32 MFMAs below);
// 32 MFMA on tile k; __syncthreads (vmcnt drain, mostly satisfied by now).
// Same swizzle as R3-R7 (0 bank conflicts).
template <int MODE>
__device__ __forceinline__ void gemm_core(
    int mtile, int ntile, int a,
    const ushort_t* __restrict__ inp, const ushort_t* __restrict__ wt,
    f32x4 (&acc)[4][4], int (&offA)[4], int (&offB)[4],
    ushort_t* ldsA, ushort_t* ldsB) {
  const int lane = threadIdx.x & 63;
  const int wv   = threadIdx.x >> 6;

  const int phoff = (MODE == 0) ? c_ph_off[a] : 0;
  const int nk    = (MODE == 0) ? c_ph_ntap[a] * 8 : 72;

  const int cl = ((lane & 7) - (lane >> 3)) & 7;
  const char* pA[4];
  const char* pB[4];
#pragma unroll
  for (int t = 0; t < 4; ++t) {
    int row = wv * 32 + t * 8 + (lane >> 3);
    int m   = mtile * 128 + row;
    size_t pix;
    if (MODE == 0) {
      if (m > 8711) m = 8711;
      int b = m / 1089, rr = m % 1089;
      int p1 = rr / 33, p2 = rr % 33;
      pix = ((size_t)(b * 34 + p1) * 34 + p2) * 512;
    } else {
      int b = m >> 12, o1 = (m >> 6) & 63, o2 = m & 63;
      pix = ((size_t)(b * 66 + o1 + 1) * 66 + (o2 + 1)) * 512;
    }
    pA[t] = (const char*)inp + pix * 2 + cl * 16;
    int n = ntile * 128 + row;
    pB[t] = (const char*)wt + (size_t)n * 1024 + cl * 16;
  }
  char* dstA[4];
  char* dstB[4];
#pragma unroll
  for (int t = 0; t < 4; ++t) {
    dstA[t] = (char*)ldsA + wv * 4096 + t * 1024;
    dstB[t] = (char*)ldsB + wv * 4096 + t * 1024;
  }

  auto stagef = [&](int kn) {
    int tap = kn >> 3, kc = kn & 7;
    int aoff, boff;
    if (MODE == 0) {
      int e = phoff + tap;
      aoff = ((int)c_tap_u1[e] * 34 + (int)c_tap_u2[e]) * 1024 + kc * 128;
      boff = (int)c_tap_pl[e] * 524288 + kc * 128;
    } else {
      int ty = (tap * 86) >> 8;           // tap/3
      int tx = tap - ty * 3;
      aoff = ((ty - 1) * 66 + (tx - 1)) * 1024 + kc * 128;
      boff = tap * 524288 + kc * 128;
    }
#pragma unroll
    for (int t = 0; t < 4; ++t) async_cp16(pA[t] + aoff, dstA[t]);
#pragma unroll
    for (int t = 0; t < 4; ++t) async_cp16(pB[t] + boff, dstB[t]);
  };

  stagef(0);
  __syncthreads();                 // tile 0 visible

#pragma unroll 1
  for (int k = 0; k < nk; ++k) {
    // 1) read all fragments of tile k (both kk halves)
    bf16x8 af[2][4], bg[2][4];
#pragma unroll
    for (int kk = 0; kk < 2; ++kk) {
      const int kx = kk << 5;
#pragma unroll
      for (int i = 0; i < 4; ++i) af[kk][i] = *reinterpret_cast<const bf16x8*>(ldsA + (offA[i] ^ kx));
#pragma unroll
      for (int j = 0; j < 4; ++j) bg[kk][j] = *reinterpret_cast<const bf16x8*>(ldsB + (offB[j] ^ kx));
    }
    __syncthreads();               // all waves finished reading LDS tile k
    // 2) stage tile k+1 (latency hidden under the MFMAs below)
    if (k + 1 < nk) stagef(k + 1);
    // 3) compute tile k
#pragma unroll
    for (int kk = 0; kk < 2; ++kk)
#pragma unroll
      for (int i = 0; i < 4; ++i)
#pragma unroll
        for (int j = 0; j < 4; ++j)
          acc[i][j] = __builtin_amdgcn_mfma_f32_16x16x32_bf16(af[kk][i], bg[kk][j], acc[i][j], 0, 0, 0);
    __syncthreads();               // vmcnt drain (mostly complete) + tile k+1 visible
  }
}

// ------------------------------------------------- conv1: unfused convT phase GEMM, XCD-swizzled
__global__ __launch_bounds__(256, 3) void gemm_conv1(
    const ushort_t* __restrict__ inp, const ushort_t* __restrict__ wt,
    const float* __restrict__ dmod, ushort_t* __restrict__ outp) {
  const int g = blockIdx.x;
  const int mtile = ((g >> 7) << 3) | (g & 7);   // 0..71
  if (mtile >= 69) return;
  const int sub   = (g >> 3) & 15;
  const int a     = sub >> 2;
  const int ntile = sub & 3;
  const int a1 = a >> 1, a2 = a & 1;

  __shared__ ushort_t ldsA[128 * 64];
  __shared__ ushort_t ldsB[128 * 64];

  const int lane = threadIdx.x & 63;
  const int wv   = threadIdx.x >> 6;
  const int wm   = wv & 1;
  const int wn   = wv >> 1;
  const int l16  = lane & 15;
  const int quad = lane >> 4;

  int offA[4], offB[4];
#pragma unroll
  for (int i = 0; i < 4; ++i) {
    int r  = wm * 64 + i * 16 + l16;
    int rn = wn * 64 + i * 16 + l16;
    offA[i] = r  * 64 + (((quad + r)  & 7) << 3);
    offB[i] = rn * 64 + (((quad + rn) & 7) << 3);
  }
  f32x4 acc[4][4];
#pragma unroll
  for (int i = 0; i < 4; ++i)
#pragma unroll
    for (int j = 0; j < 4; ++j) acc[i][j] = (f32x4){0.f, 0.f, 0.f, 0.f};

  gemm_core<0>(mtile, ntile, a, inp, wt, acc, offA, offB, ldsA, ldsB);

  int co_[4];
#pragma unroll
  for (int j = 0; j < 4; ++j) co_[j] = ntile * 128 + wn * 64 + j * 16 + l16;
#pragma unroll
  for (int i = 0; i < 4; ++i) {
#pragma unroll
    for (int r = 0; r < 4; ++r) {
      int m = mtile * 128 + wm * 64 + i * 16 + quad * 4 + r;
      if (m < 8712) {
        int b = m / 1089, rr = m % 1089;
        int p1 = rr / 33, p2 = rr % 33;
        if ((a1 == 0 || p1 < 32) && (a2 == 0 || p2 < 32)) {
          int o1 = 2 * p1 + a1, o2 = 2 * p2 + a2;
          size_t ob = ((size_t)(b * 67 + o1 + 1) * 67 + (o2 + 1)) * 512;
#pragma unroll
          for (int j = 0; j < 4; ++j)
            outp[ob + co_[j]] = f2bf(acc[i][j][r] * dmod[b * 512 + co_[j]]);
        }
      }
    }
  }
}

// ------------------------------------------------- conv2 + fused ToRGB, XCD-swizzled
__global__ __launch_bounds__(256, 3) void gemm_conv2(
    const ushort_t* __restrict__ inp, const ushort_t* __restrict__ wt,
    const float* __restrict__ dmod, const float* __restrict__ noise,
    const float* __restrict__ nw, const float* __restrict__ bias,
    const float* __restrict__ srgb, const float* __restrict__ wrgb,
    float* __restrict__ rgbpart) {
  const int g = blockIdx.x;
  const int mtile = ((g >> 5) << 3) | (g & 7);
  const int ntile = (g >> 3) & 3;

  __shared__ ushort_t ldsA[128 * 64];
  __shared__ ushort_t ldsB[128 * 64];

  const int lane = threadIdx.x & 63;
  const int wv   = threadIdx.x >> 6;
  const int wm   = wv & 1;
  const int wn   = wv >> 1;
  const int l16  = lane & 15;
  const int quad = lane >> 4;

  int offA[4], offB[4];
#pragma unroll
  for (int i = 0; i < 4; ++i) {
    int r  = wm * 64 + i * 16 + l16;
    int rn = wn * 64 + i * 16 + l16;
    offA[i] = r  * 64 + (((quad + r)  & 7) << 3);
    offB[i] = rn * 64 + (((quad + rn) & 7) << 3);
  }
  f32x4 acc[4][4];
#pragma unroll
  for (int i = 0; i < 4; ++i)
#pragma unroll
    for (int j = 0; j < 4; ++j) acc[i][j] = (f32x4){0.f, 0.f, 0.f, 0.f};

  gemm_core<1>(mtile, ntile, 0, inp, wt, acc, offA, offB, ldsA, ldsB);

  // ---- epilogue: demod + noise + bias + lrelu*sqrt2 + srgb scale, then RGB projection
  const int b = mtile >> 5;
  int co_[4];
#pragma unroll
  for (int j = 0; j < 4; ++j) co_[j] = ntile * 128 + wn * 64 + j * 16 + l16;
  const float nwv = nw[0];
  float dj_[4], sj_[4], bj_[4], wr[3][4];
#pragma unroll
  for (int j = 0; j < 4; ++j) {
    dj_[j] = dmod[b * 512 + co_[j]];
    sj_[j] = srgb[b * 512 + co_[j]] * SCALE_RGB;
    bj_[j] = bias[co_[j]];
#pragma unroll
    for (int c = 0; c < 3; ++c) wr[c][j] = wrgb[c * 512 + co_[j]];
  }
#pragma unroll
  for (int i = 0; i < 4; ++i) {
#pragma unroll
    for (int r = 0; r < 4; ++r) {
      int m = mtile * 128 + wm * 64 + i * 16 + quad * 4 + r;
      int o1 = (m >> 6) & 63, o2 = m & 63;
      float nz = nwv * noise[(b << 12) + (o1 << 6) + o2];
      float vv[4];
#pragma unroll
      for (int j = 0; j < 4; ++j) {
        float v = acc[i][j][r] * dj_[j] + nz + bj_[j];
        v = (v >= 0.f ? v : 0.2f * v) * SQRT2_F;
        vv[j] = v * sj_[j];
      }
#pragma unroll
      for (int c = 0; c < 3; ++c) {
        float s = vv[0] * wr[c][0] + vv[1] * wr[c][1] + vv[2] * wr[c][2] + vv[3] * wr[c][3];
        s += __shfl_xor(s, 1);
        s += __shfl_xor(s, 2);
        s += __shfl_xor(s, 4);
        s += __shfl_xor(s, 8);
        if (l16 == 0) atomicAdd(&rgbpart[c * 32768 + m], s);
      }
    }
  }
}

// ------------------------------------------------- blur(4-tap separable) + noise + bias + lrelu + s2-scale
__global__ __launch_bounds__(256) void blur_noise_act(
    const ushort_t* __restrict__ y1pad, const float* __restrict__ noise,
    const float* __restrict__ nw, const float* __restrict__ bias,
    const float* __restrict__ s2, ushort_t* __restrict__ out1pad) {
  const int cg  = threadIdx.x & 63;                       // channel octet
  const int pg  = blockIdx.x * 4 + (threadIdx.x >> 6);    // 0..4095
  const int b   = pg >> 9;
  const int q1  = (pg >> 3) & 63;
  const int q2g = (pg & 7) * 8;                           // 8 consecutive output cols
  const float cw[4] = {0.25f, 0.75f, 0.75f, 0.25f};

  float acc[8][8];
#pragma unroll
  for (int j = 0; j < 8; ++j)
#pragma unroll
    for (int e = 0; e < 8; ++e) acc[j][e] = 0.f;

#pragma unroll
  for (int t2 = 0; t2 < 11; ++t2) {
    int cc = q2g + t2;
    float vt[8];
#pragma unroll
    for (int e = 0; e < 8; ++e) vt[e] = 0.f;
#pragma unroll
    for (int t1 = 0; t1 < 4; ++t1) {
      const ushort_t* p = y1pad + ((size_t)(b * 67 + q1 + t1) * 67 + cc) * 512 + cg * 8;
      ushort_t v[8];
      *(uint4*)v = *(const uint4*)p;
#pragma unroll
      for (int e = 0; e < 8; ++e) vt[e] += cw[t1] * bf2f(v[e]);
    }
#pragma unroll
    for (int j = 0; j < 8; ++j) {
      int t = t2 - j;
      if (t >= 0 && t < 4) {
#pragma unroll
        for (int e = 0; e < 8; ++e) acc[j][e] += cw[t] * vt[e];
      }
    }
  }

  const float nwv = nw[0];
  float bj[8], sj[8];
#pragma unroll
  for (int e = 0; e < 8; ++e) {
    bj[e] = bias[cg * 8 + e];
    sj[e] = s2[b * 512 + cg * 8 + e] * SCALE_CONV;
  }
#pragma unroll
  for (int j = 0; j < 8; ++j) {
    int q2 = q2g + j;
    float nz = nwv * noise[(b << 12) + (q1 << 6) + q2];
    ushort_t o[8];
#pragma unroll
    for (int e = 0; e < 8; ++e) {
      float v = acc[j][e] + nz + bj[e];
      v = (v >= 0.f ? v : 0.2f * v) * SQRT2_F * sj[e];
      o[e] = f2bf(v);
    }
    *(uint4*)(out1pad + ((size_t)(b * 66 + q1 + 1) * 66 + (q2 + 1)) * 512 + cg * 8) = *(uint4*)o;
  }
}

// ------------------------------------------------- final: rgbpart + bias + skip upfirdn(up=2) -> out
__global__ __launch_bounds__(256) void rgb_finish(
    const float* __restrict__ rgbpart, const float* __restrict__ brgb,
    const float* __restrict__ skip, float* __restrict__ out) {
  const int t = blockIdx.x * 256 + threadIdx.x;   // 3*32768
  if (t >= 98304) return;
  const int m = t & 32767, c = t >> 15;
  const int b = m >> 12, o1 = (m >> 6) & 63, o2 = m & 63;
  int P1 = o1 >> 1, P2 = o2 >> 1;
  int jy0, jy1, jx0, jx1;
  float wy0, wy1, wx0, wx1;
  if ((o1 & 1) == 0) { jy0 = P1 - 1; wy0 = .25f; jy1 = P1;     wy1 = .75f; }
  else               { jy0 = P1;     wy0 = .75f; jy1 = P1 + 1; wy1 = .25f; }
  if ((o2 & 1) == 0) { jx0 = P2 - 1; wx0 = .25f; jx1 = P2;     wx1 = .75f; }
  else               { jx0 = P2;     wx0 = .75f; jx1 = P2 + 1; wx1 = .25f; }
  const float* sp = skip + (size_t)(b * 3 + c) * 1024;
  float sv = 0.f;
  if (jy0 >= 0 && jy0 < 32) {
    if (jx0 >= 0 && jx0 < 32) sv += wy0 * wx0 * sp[jy0 * 32 + jx0];
    if (jx1 >= 0 && jx1 < 32) sv += wy0 * wx1 * sp[jy0 * 32 + jx1];
  }
  if (jy1 >= 0 && jy1 < 32) {
    if (jx0 >= 0 && jx0 < 32) sv += wy1 * wx0 * sp[jy1 * 32 + jx0];
    if (jx1 >= 0 && jx1 < 32) sv += wy1 * wx1 * sp[jy1 * 32 + jx1];
  }
  out[((size_t)(b * 3 + c) << 12) + (o1 << 6) + o2] = rgbpart[c * 32768 + m] + brgb[c] + sv;
}

// ------------------------------------------------- launch
extern "C" void kernel_launch(void* const* d_in, const int* in_sizes, int n_in,
                              void* d_out, int out_size, void* d_ws, size_t ws_size,
                              hipStream_t stream) {
  const float* x    = (const float*)d_in[0];
  const float* skip = (const float*)d_in[1];
  const float* w1   = (const float*)d_in[2];
  const float* b1   = (const float*)d_in[3];
  const float* s1   = (const float*)d_in[4];
  const float* nw1  = (const float*)d_in[5];
  const float* n1   = (const float*)d_in[6];
  const float* w2   = (const float*)d_in[7];
  const float* b2   = (const float*)d_in[8];
  const float* s2   = (const float*)d_in[9];
  const float* nw2  = (const float*)d_in[10];
  const float* n2   = (const float*)d_in[11];
  const float* wrgb = (const float*)d_in[12];
  const float* brgb = (const float*)d_in[13];
  const float* srgb = (const float*)d_in[14];

  char* ws = (char*)d_ws;
  const size_t XPAD_B  = (size_t)8 * 34 * 34 * 512 * 2;   //  9,469,952
  const size_t Y1PAD_B = (size_t)8 * 67 * 67 * 512 * 2;   // 36,773,888
  const size_t OUT1_B  = (size_t)8 * 66 * 66 * 512 * 2;   // 35,684,352
  const size_t WT_B    = (size_t)9 * 512 * 512 * 2;       //  4,718,592
  size_t off = 0;
  ushort_t* xpad1   = (ushort_t*)(ws + off); off += XPAD_B;
  ushort_t* y1pad   = (ushort_t*)(ws + off); off += Y1PAD_B;
  ushort_t* out1pad = (ushort_t*)(ws + off); off += OUT1_B;
  ushort_t* wt1     = (ushort_t*)(ws + off); off += WT_B;
  ushort_t* wt2     = (ushort_t*)(ws + off); off += WT_B;
  float*    d1      = (float*)(ws + off);    off += 8 * 512 * 4;
  float*    d2      = (float*)(ws + off);    off += 8 * 512 * 4;
  float*    rgbpart = (float*)(ws + off);    off += 3 * 32768 * 4;
  // wsqT1/2 alias y1pad (consumed by demod3 before border_zero/gemm touch y1pad)
  float*    wsqT1  = (float*)y1pad;
  float*    wsqT2  = wsqT1 + 512 * 512;

  prep_all<<<2304, 256, 0, stream>>>(x, s1, xpad1, w1, w2, wt1, wt2, wsqT1, wsqT2);
  demod3<<<dim3(8, 8, 2), 256, 0, stream>>>(wsqT1, s1, d1, wsqT2, s2, d2);
  border_zero<<<dim3(66, 8, 4), 256, 0, stream>>>(xpad1, y1pad, out1pad, rgbpart);

  // conv1: unfused convT (4 phases, 9 taps total), XCD-swizzled -> y1pad (raw * demod)
  gemm_conv1<<<1152, 256, 0, stream>>>(xpad1, wt1, d1, y1pad);
  // blur + noise + bias + lrelu + s2-scale -> out1pad
  blur_noise_act<<<1024, 256, 0, stream>>>(y1pad, n1, nw1, b1, s2, out1pad);
  // conv2 (XCD-swizzled) + fused ToRGB partial reduction -> rgbpart
  gemm_conv2<<<1024, 256, 0, stream>>>(
      out1pad, wt2, d2, n2, nw2, b2, srgb, wrgb, rgbpart);
  // final: rgb bias + skip upsample
  rgb_finish<<<384, 256, 0, stream>>>(rgbpart, brgb, skip, (float*)d_out);
}

// Round 11
// 358.543 us; speedup vs baseline: 3.1138x; 1.1455x over previous
//
#include <hip/hip_runtime.h>
#include <stdint.h>

typedef unsigned short ushort_t;
typedef unsigned int uint_t;
typedef __bf16 bf16x8 __attribute__((ext_vector_type(8)));
typedef float f32x4 __attribute__((ext_vector_type(4)));

#define GLOBAL_AS __attribute__((address_space(1)))
#define LDS_AS    __attribute__((address_space(3)))

#define SCALE_CONV 0.014731391f   /* 1/sqrt(512*9) */
#define SCALE_RGB  0.044194174f   /* 1/sqrt(512)   */
#define SQRT2_F    1.41421356237f

// ---------------------------------------------------------------- helpers
__device__ __forceinline__ void async_cp16(const void* g, void* l) {
  __builtin_amdgcn_global_load_lds((const GLOBAL_AS uint_t*)g,
                                   (LDS_AS uint_t*)l, 16, 0, 0);
}
__device__ __forceinline__ ushort_t f2bf(float v) {
  union { float f; uint_t u; } c; c.f = v;
  uint_t r = c.u + 0x7fffu + ((c.u >> 16) & 1u);   // RNE
  return (ushort_t)(r >> 16);
}
__device__ __forceinline__ float bf2f(ushort_t u) {
  union { uint_t u; float f; } c; c.u = ((uint_t)u) << 16;
  return c.f;
}

// ------------------------------------------------- prep (merged): x->xpad1 and w1/w2->wt/wsqT
__global__ __launch_bounds__(256) void prep_all(
    const float* __restrict__ x, const float* __restrict__ s1,
    ushort_t* __restrict__ xpad,
    const float* __restrict__ w1, const float* __restrict__ w2,
    ushort_t* __restrict__ wt1, ushort_t* __restrict__ wt2,
    float* __restrict__ wsqT1, float* __restrict__ wsqT2) {
  if (blockIdx.x < 256) {
    __shared__ ushort_t t[32 * 520];
    const int b  = blockIdx.x >> 5;
    const int j1 = blockIdx.x & 31;
    for (int idx = threadIdx.x; idx < 512 * 32; idx += 256) {
      int ci = idx >> 5, j2 = idx & 31;
      float v = x[(size_t)(b * 512 + ci) * 1024 + j1 * 32 + j2];
      v *= s1[b * 512 + ci] * SCALE_CONV;
      t[j2 * 520 + ci] = f2bf(v);
    }
    __syncthreads();
    for (int idx = threadIdx.x; idx < 32 * 512; idx += 256) {
      int j2 = idx >> 9, ci = idx & 511;
      xpad[((size_t)(b * 34 + j1 + 1) * 34 + (j2 + 1)) * 512 + ci] = t[j2 * 520 + ci];
    }
    return;
  }
  int t = (blockIdx.x - 256) * 256 + threadIdx.x;   // 2*512*512
  const float* w  = (t < 262144) ? w1 : w2;
  ushort_t*   wt  = (t < 262144) ? wt1 : wt2;
  float*      wq  = (t < 262144) ? wsqT1 : wsqT2;
  int tt = t & 262143;
  int ci = tt & 511, co = tt >> 9;
  const float* wp = w + (size_t)(co * 512 + ci) * 9;
  float sq = 0.f;
#pragma unroll
  for (int u = 0; u < 9; ++u) {
    float v = wp[u];
    sq += v * v;
    wt[((size_t)u * 512 + co) * 512 + ci] = f2bf(v);
  }
  wq[ci * 512 + co] = sq;
}

// ------------------------------------------------- aux: demod (z=0,1) + pad-border zero (z=2..4)
__global__ __launch_bounds__(256) void aux_demod_border(
    const float* __restrict__ wsqT1, const float* __restrict__ s1, float* __restrict__ d1,
    const float* __restrict__ wsqT2, const float* __restrict__ s2, float* __restrict__ d2,
    ushort_t* __restrict__ xpad, ushort_t* __restrict__ ypad, ushort_t* __restrict__ opad) {
  const int z = blockIdx.z;
  if (z < 2) {
    if (blockIdx.x >= 8) return;
    const float* wq = z ? wsqT2 : wsqT1;
    const float* s  = z ? s2 : s1;
    float*       d  = z ? d2 : d1;
    const int b   = blockIdx.y;
    const int co  = blockIdx.x * 64 + (threadIdx.x & 63);
    const int cig = threadIdx.x >> 6;
    __shared__ float ssq[512];
    __shared__ float red[4][64];
    for (int i = threadIdx.x; i < 512; i += 256) {
      float v = s[b * 512 + i];
      ssq[i] = v * v;
    }
    __syncthreads();
    float a = 0.f;
#pragma unroll 4
    for (int ci = cig * 128; ci < cig * 128 + 128; ++ci)
      a += wq[ci * 512 + co] * ssq[ci];
    red[cig][threadIdx.x & 63] = a;
    __syncthreads();
    if (cig == 0) {
      int l = threadIdx.x & 63;
      float tot = red[0][l] + red[1][l] + red[2][l] + red[3][l];
      d[b * 512 + co] = rsqrtf(tot * (1.f / 4608.f) + 1e-8f);
    }
    return;
  }
  const int z2 = z - 2;
  ushort_t* p = (z2 == 0) ? xpad : (z2 == 1 ? ypad : opad);
  const int W = (z2 == 0) ? 34 : (z2 == 1 ? 67 : 66);
  const int nb = 4 * W - 4;
  const int t = blockIdx.x * 256 + threadIdx.x;
  const int pix = t >> 6, ch = (t & 63) * 8;
  if (pix >= nb) return;
  const int b = blockIdx.y;
  int y, x;
  if (pix < W)          { y = 0;     x = pix; }
  else if (pix < 2 * W) { y = W - 1; x = pix - W; }
  else { int q = pix - 2 * W; y = 1 + (q >> 1); x = (q & 1) ? W - 1 : 0; }
  uint4 z4 = {0, 0, 0, 0};
  *(uint4*)(p + ((size_t)(b * W + y) * W + x) * 512 + ch) = z4;
}

// ------------------------------------------------- conv1 phase tap tables (convT stride-2, k=3)
__constant__ int           c_ph_off[4]  = {0, 4, 6, 8};
__constant__ int           c_ph_ntap[4] = {4, 2, 2, 1};
__constant__ unsigned char c_tap_u1[9]  = {0,0,1,1, 0,1, 1,1, 1};
__constant__ unsigned char c_tap_u2[9]  = {0,1,0,1, 1,1, 0,1, 1};
__constant__ unsigned char c_tap_pl[9]  = {8,6,2,0, 7,1, 5,3, 4};

// ------------------------------------------------- conv1: unfused convT phase GEMM (BK=64, XCD-swizzled)
// R7-proven K-loop. (256,4): 4 blocks/CU to fill the phase-imbalance tail (blocks run 8-32 k-steps).
__global__ __launch_bounds__(256, 4) void gemm_conv1(
    const ushort_t* __restrict__ inp, const ushort_t* __restrict__ wt,
    const float* __restrict__ dmod, ushort_t* __restrict__ outp) {
  const int g = blockIdx.x;
  const int mtile = ((g >> 7) << 3) | (g & 7);   // 0..71
  if (mtile >= 69) return;
  const int sub   = (g >> 3) & 15;
  const int a     = sub >> 2;
  const int ntile = sub & 3;
  const int a1 = a >> 1, a2 = a & 1;

  __shared__ ushort_t ldsA[128 * 64];
  __shared__ ushort_t ldsB[128 * 64];

  const int lane = threadIdx.x & 63;
  const int wv   = threadIdx.x >> 6;
  const int wm   = wv & 1;
  const int wn   = wv >> 1;
  const int l16  = lane & 15;
  const int quad = lane >> 4;

  const int cl = ((lane & 7) - (lane >> 3)) & 7;
  const char* pA[4];
  const char* pB[4];
#pragma unroll
  for (int t = 0; t < 4; ++t) {
    int row = wv * 32 + t * 8 + (lane >> 3);
    int m   = mtile * 128 + row;
    if (m > 8711) m = 8711;
    int b = m / 1089, rr = m % 1089;
    int p1 = rr / 33, p2 = rr % 33;
    size_t pix = ((size_t)(b * 34 + p1) * 34 + p2) * 512;
    pA[t] = (const char*)inp + pix * 2 + cl * 16;
    int n = ntile * 128 + row;
    pB[t] = (const char*)wt + (size_t)n * 1024 + cl * 16;
  }
  char* dstA[4];
  char* dstB[4];
#pragma unroll
  for (int t = 0; t < 4; ++t) {
    dstA[t] = (char*)ldsA + wv * 4096 + t * 1024;
    dstB[t] = (char*)ldsB + wv * 4096 + t * 1024;
  }

  int offA[4], offB[4];
#pragma unroll
  for (int i = 0; i < 4; ++i) {
    int r  = wm * 64 + i * 16 + l16;
    int rn = wn * 64 + i * 16 + l16;
    offA[i] = r  * 64 + (((quad + r)  & 7) << 3);
    offB[i] = rn * 64 + (((quad + rn) & 7) << 3);
  }

  f32x4 acc[4][4];
#pragma unroll
  for (int i = 0; i < 4; ++i)
#pragma unroll
    for (int j = 0; j < 4; ++j) acc[i][j] = (f32x4){0.f, 0.f, 0.f, 0.f};

  const int ntap = c_ph_ntap[a];
#pragma unroll 1
  for (int ti = 0; ti < ntap; ++ti) {
    int e = c_ph_off[a] + ti;
    int aoff = ((int)c_tap_u1[e] * 34 + (int)c_tap_u2[e]) * 1024;
    int boff = (int)c_tap_pl[e] * 524288;
#pragma unroll 1
    for (int kc = 0; kc < 8; ++kc) {
      const int koff = kc * 128;
      __syncthreads();
#pragma unroll
      for (int t = 0; t < 4; ++t) async_cp16(pA[t] + aoff + koff, dstA[t]);
#pragma unroll
      for (int t = 0; t < 4; ++t) async_cp16(pB[t] + boff + koff, dstB[t]);
      __syncthreads();
#pragma unroll
      for (int kk = 0; kk < 2; ++kk) {
        const int kx = kk << 5;
        bf16x8 af[4], bg[4];
#pragma unroll
        for (int i = 0; i < 4; ++i) af[i] = *reinterpret_cast<const bf16x8*>(ldsA + (offA[i] ^ kx));
#pragma unroll
        for (int j = 0; j < 4; ++j) bg[j] = *reinterpret_cast<const bf16x8*>(ldsB + (offB[j] ^ kx));
#pragma unroll
        for (int i = 0; i < 4; ++i)
#pragma unroll
          for (int j = 0; j < 4; ++j)
            acc[i][j] = __builtin_amdgcn_mfma_f32_16x16x32_bf16(af[i], bg[j], acc[i][j], 0, 0, 0);
      }
    }
  }

  int co_[4];
#pragma unroll
  for (int j = 0; j < 4; ++j) co_[j] = ntile * 128 + wn * 64 + j * 16 + l16;

#pragma unroll
  for (int i = 0; i < 4; ++i) {
#pragma unroll
    for (int r = 0; r < 4; ++r) {
      int m = mtile * 128 + wm * 64 + i * 16 + quad * 4 + r;
      if (m < 8712) {
        int b = m / 1089, rr = m % 1089;
        int p1 = rr / 33, p2 = rr % 33;
        if ((a1 == 0 || p1 < 32) && (a2 == 0 || p2 < 32)) {
          int o1 = 2 * p1 + a1, o2 = 2 * p2 + a2;
          size_t ob = ((size_t)(b * 67 + o1 + 1) * 67 + (o2 + 1)) * 512;
#pragma unroll
          for (int j = 0; j < 4; ++j)
            outp[ob + co_[j]] = f2bf(acc[i][j][r] * dmod[b * 512 + co_[j]]);
        }
      }
    }
  }
}

// ------------------------------------------------- conv2: R7 K-loop + fused ToRGB (no atomics)
// Partial RGB written to 8 disjoint slabs rgbpart[(ntile*2+wn)][c][m]; rgb_finish sums them.
__global__ __launch_bounds__(256, 3) void gemm_conv2(
    const ushort_t* __restrict__ inp, const ushort_t* __restrict__ wt,
    const float* __restrict__ dmod, const float* __restrict__ noise,
    const float* __restrict__ nw, const float* __restrict__ bias,
    const float* __restrict__ srgb, const float* __restrict__ wrgb,
    float* __restrict__ rgbpart) {
  const int g = blockIdx.x;
  const int mtile = ((g >> 5) << 3) | (g & 7);
  const int ntile = (g >> 3) & 3;

  __shared__ ushort_t ldsA[128 * 64];
  __shared__ ushort_t ldsB[128 * 64];

  const int lane = threadIdx.x & 63;
  const int wv   = threadIdx.x >> 6;
  const int wm   = wv & 1;
  const int wn   = wv >> 1;
  const int l16  = lane & 15;
  const int quad = lane >> 4;

  const int cl = ((lane & 7) - (lane >> 3)) & 7;
  const char* pA[4];
  const char* pB[4];
#pragma unroll
  for (int t = 0; t < 4; ++t) {
    int row = wv * 32 + t * 8 + (lane >> 3);
    int m   = mtile * 128 + row;
    int b = m >> 12, o1 = (m >> 6) & 63, o2 = m & 63;
    size_t pix = ((size_t)(b * 66 + o1 + 1) * 66 + (o2 + 1)) * 512;
    pA[t] = (const char*)inp + pix * 2 + cl * 16;
    int n = ntile * 128 + row;
    pB[t] = (const char*)wt + (size_t)n * 1024 + cl * 16;
  }
  char* dstA[4];
  char* dstB[4];
#pragma unroll
  for (int t = 0; t < 4; ++t) {
    dstA[t] = (char*)ldsA + wv * 4096 + t * 1024;
    dstB[t] = (char*)ldsB + wv * 4096 + t * 1024;
  }

  int offA[4], offB[4];
#pragma unroll
  for (int i = 0; i < 4; ++i) {
    int r  = wm * 64 + i * 16 + l16;
    int rn = wn * 64 + i * 16 + l16;
    offA[i] = r  * 64 + (((quad + r)  & 7) << 3);
    offB[i] = rn * 64 + (((quad + rn) & 7) << 3);
  }

  f32x4 acc[4][4];
#pragma unroll
  for (int i = 0; i < 4; ++i)
#pragma unroll
    for (int j = 0; j < 4; ++j) acc[i][j] = (f32x4){0.f, 0.f, 0.f, 0.f};

#pragma unroll 1
  for (int ti = 0; ti < 9; ++ti) {
    int aoff = ((ti / 3 - 1) * 66 + (ti % 3 - 1)) * 1024;
    int boff = ti * 524288;
#pragma unroll 1
    for (int kc = 0; kc < 8; ++kc) {
      const int koff = kc * 128;
      __syncthreads();
#pragma unroll
      for (int t = 0; t < 4; ++t) async_cp16(pA[t] + aoff + koff, dstA[t]);
#pragma unroll
      for (int t = 0; t < 4; ++t) async_cp16(pB[t] + boff + koff, dstB[t]);
      __syncthreads();
#pragma unroll
      for (int kk = 0; kk < 2; ++kk) {
        const int kx = kk << 5;
        bf16x8 af[4], bg[4];
#pragma unroll
        for (int i = 0; i < 4; ++i) af[i] = *reinterpret_cast<const bf16x8*>(ldsA + (offA[i] ^ kx));
#pragma unroll
        for (int j = 0; j < 4; ++j) bg[j] = *reinterpret_cast<const bf16x8*>(ldsB + (offB[j] ^ kx));
#pragma unroll
        for (int i = 0; i < 4; ++i)
#pragma unroll
          for (int j = 0; j < 4; ++j)
            acc[i][j] = __builtin_amdgcn_mfma_f32_16x16x32_bf16(af[i], bg[j], acc[i][j], 0, 0, 0);
      }
    }
  }

  // ---- epilogue: demod + noise + bias + lrelu*sqrt2 + srgb scale, then RGB projection
  const int b = mtile >> 5;
  int co_[4];
#pragma unroll
  for (int j = 0; j < 4; ++j) co_[j] = ntile * 128 + wn * 64 + j * 16 + l16;
  const float nwv = nw[0];
  float dj_[4], sj_[4], bj_[4], wr[3][4];
#pragma unroll
  for (int j = 0; j < 4; ++j) {
    dj_[j] = dmod[b * 512 + co_[j]];
    sj_[j] = srgb[b * 512 + co_[j]] * SCALE_RGB;
    bj_[j] = bias[co_[j]];
#pragma unroll
    for (int c = 0; c < 3; ++c) wr[c][j] = wrgb[c * 512 + co_[j]];
  }
  float* slab = rgbpart + (size_t)(ntile * 2 + wn) * 98304;
#pragma unroll
  for (int i = 0; i < 4; ++i) {
#pragma unroll
    for (int r = 0; r < 4; ++r) {
      int m = mtile * 128 + wm * 64 + i * 16 + quad * 4 + r;
      int o1 = (m >> 6) & 63, o2 = m & 63;
      float nz = nwv * noise[(b << 12) + (o1 << 6) + o2];
      float vv[4];
#pragma unroll
      for (int j = 0; j < 4; ++j) {
        float v = acc[i][j][r] * dj_[j] + nz + bj_[j];
        v = (v >= 0.f ? v : 0.2f * v) * SQRT2_F;
        vv[j] = v * sj_[j];
      }
#pragma unroll
      for (int c = 0; c < 3; ++c) {
        float s = vv[0] * wr[c][0] + vv[1] * wr[c][1] + vv[2] * wr[c][2] + vv[3] * wr[c][3];
        s += __shfl_xor(s, 1);
        s += __shfl_xor(s, 2);
        s += __shfl_xor(s, 4);
        s += __shfl_xor(s, 8);
        if (l16 == 0) slab[c * 32768 + m] = s;
      }
    }
  }
}

// ------------------------------------------------- blur(4-tap separable) + noise + bias + lrelu + s2-scale
__global__ __launch_bounds__(256) void blur_noise_act(
    const ushort_t* __restrict__ y1pad, const float* __restrict__ noise,
    const float* __restrict__ nw, const float* __restrict__ bias,
    const float* __restrict__ s2, ushort_t* __restrict__ out1pad) {
  const int cg  = threadIdx.x & 63;                       // channel octet
  const int pg  = blockIdx.x * 4 + (threadIdx.x >> 6);    // 0..4095
  const int b   = pg >> 9;
  const int q1  = (pg >> 3) & 63;
  const int q2g = (pg & 7) * 8;                           // 8 consecutive output cols
  const float cw[4] = {0.25f, 0.75f, 0.75f, 0.25f};

  float acc[8][8];
#pragma unroll
  for (int j = 0; j < 8; ++j)
#pragma unroll
    for (int e = 0; e < 8; ++e) acc[j][e] = 0.f;

#pragma unroll
  for (int t2 = 0; t2 < 11; ++t2) {
    int cc = q2g + t2;
    float vt[8];
#pragma unroll
    for (int e = 0; e < 8; ++e) vt[e] = 0.f;
#pragma unroll
    for (int t1 = 0; t1 < 4; ++t1) {
      const ushort_t* p = y1pad + ((size_t)(b * 67 + q1 + t1) * 67 + cc) * 512 + cg * 8;
      ushort_t v[8];
      *(uint4*)v = *(const uint4*)p;
#pragma unroll
      for (int e = 0; e < 8; ++e) vt[e] += cw[t1] * bf2f(v[e]);
    }
#pragma unroll
    for (int j = 0; j < 8; ++j) {
      int t = t2 - j;
      if (t >= 0 && t < 4) {
#pragma unroll
        for (int e = 0; e < 8; ++e) acc[j][e] += cw[t] * vt[e];
      }
    }
  }

  const float nwv = nw[0];
  float bj[8], sj[8];
#pragma unroll
  for (int e = 0; e < 8; ++e) {
    bj[e] = bias[cg * 8 + e];
    sj[e] = s2[b * 512 + cg * 8 + e] * SCALE_CONV;
  }
#pragma unroll
  for (int j = 0; j < 8; ++j) {
    int q2 = q2g + j;
    float nz = nwv * noise[(b << 12) + (q1 << 6) + q2];
    ushort_t o[8];
#pragma unroll
    for (int e = 0; e < 8; ++e) {
      float v = acc[j][e] + nz + bj[e];
      v = (v >= 0.f ? v : 0.2f * v) * SQRT2_F * sj[e];
      o[e] = f2bf(v);
    }
    *(uint4*)(out1pad + ((size_t)(b * 66 + q1 + 1) * 66 + (q2 + 1)) * 512 + cg * 8) = *(uint4*)o;
  }
}

// ------------------------------------------------- final: sum 8 rgb slabs + bias + skip upfirdn -> out
__global__ __launch_bounds__(256) void rgb_finish(
    const float* __restrict__ rgbpart, const float* __restrict__ brgb,
    const float* __restrict__ skip, float* __restrict__ out) {
  const int t = blockIdx.x * 256 + threadIdx.x;   // 3*32768
  if (t >= 98304) return;
  const int m = t & 32767, c = t >> 15;
  const int b = m >> 12, o1 = (m >> 6) & 63, o2 = m & 63;
  float v3 = 0.f;
#pragma unroll
  for (int p = 0; p < 8; ++p) v3 += rgbpart[(size_t)p * 98304 + t];
  int P1 = o1 >> 1, P2 = o2 >> 1;
  int jy0, jy1, jx0, jx1;
  float wy0, wy1, wx0, wx1;
  if ((o1 & 1) == 0) { jy0 = P1 - 1; wy0 = .25f; jy1 = P1;     wy1 = .75f; }
  else               { jy0 = P1;     wy0 = .75f; jy1 = P1 + 1; wy1 = .25f; }
  if ((o2 & 1) == 0) { jx0 = P2 - 1; wx0 = .25f; jx1 = P2;     wx1 = .75f; }
  else               { jx0 = P2;     wx0 = .75f; jx1 = P2 + 1; wx1 = .25f; }
  const float* sp = skip + (size_t)(b * 3 + c) * 1024;
  float sv = 0.f;
  if (jy0 >= 0 && jy0 < 32) {
    if (jx0 >= 0 && jx0 < 32) sv += wy0 * wx0 * sp[jy0 * 32 + jx0];
    if (jx1 >= 0 && jx1 < 32) sv += wy0 * wx1 * sp[jy0 * 32 + jx1];
  }
  if (jy1 >= 0 && jy1 < 32) {
    if (jx0 >= 0 && jx0 < 32) sv += wy1 * wx0 * sp[jy1 * 32 + jx0];
    if (jx1 >= 0 && jx1 < 32) sv += wy1 * wx1 * sp[jy1 * 32 + jx1];
  }
  out[((size_t)(b * 3 + c) << 12) + (o1 << 6) + o2] = v3 + brgb[c] + sv;
}

// ------------------------------------------------- launch
extern "C" void kernel_launch(void* const* d_in, const int* in_sizes, int n_in,
                              void* d_out, int out_size, void* d_ws, size_t ws_size,
                              hipStream_t stream) {
  const float* x    = (const float*)d_in[0];
  const float* skip = (const float*)d_in[1];
  const float* w1   = (const float*)d_in[2];
  const float* b1   = (const float*)d_in[3];
  const float* s1   = (const float*)d_in[4];
  const float* nw1  = (const float*)d_in[5];
  const float* n1   = (const float*)d_in[6];
  const float* w2   = (const float*)d_in[7];
  const float* b2   = (const float*)d_in[8];
  const float* s2   = (const float*)d_in[9];
  const float* nw2  = (const float*)d_in[10];
  const float* n2   = (const float*)d_in[11];
  const float* wrgb = (const float*)d_in[12];
  const float* brgb = (const float*)d_in[13];
  const float* srgb = (const float*)d_in[14];

  char* ws = (char*)d_ws;
  const size_t XPAD_B  = (size_t)8 * 34 * 34 * 512 * 2;   //  9,469,952
  const size_t Y1PAD_B = (size_t)8 * 67 * 67 * 512 * 2;   // 36,773,888
  const size_t OUT1_B  = (size_t)8 * 66 * 66 * 512 * 2;   // 35,684,352
  const size_t WT_B    = (size_t)9 * 512 * 512 * 2;       //  4,718,592
  size_t off = 0;
  ushort_t* xpad1   = (ushort_t*)(ws + off); off += XPAD_B;
  ushort_t* y1pad   = (ushort_t*)(ws + off); off += Y1PAD_B;
  ushort_t* out1pad = (ushort_t*)(ws + off); off += OUT1_B;
  ushort_t* wt1     = (ushort_t*)(ws + off); off += WT_B;
  ushort_t* wt2     = (ushort_t*)(ws + off); off += WT_B;
  float*    d1      = (float*)(ws + off);    off += 8 * 512 * 4;
  float*    d2      = (float*)(ws + off);    off += 8 * 512 * 4;
  float*    rgbpart = (float*)(ws + off);    off += (size_t)8 * 98304 * 4;  // 3 MB
  // wsqT1/2 alias y1pad (consumed by aux demod before borders/gemm touch y1pad)
  float*    wsqT1  = (float*)y1pad;
  float*    wsqT2  = wsqT1 + 512 * 512;

  prep_all<<<2304, 256, 0, stream>>>(x, s1, xpad1, w1, w2, wt1, wt2, wsqT1, wsqT2);
  // demod (z=0,1) + pad-border zero (z=2..4)
  aux_demod_border<<<dim3(66, 8, 5), 256, 0, stream>>>(
      wsqT1, s1, d1, wsqT2, s2, d2, xpad1, y1pad, out1pad);

  // conv1: unfused convT (4 phases, 9 taps total), XCD-swizzled -> y1pad (raw * demod)
  gemm_conv1<<<1152, 256, 0, stream>>>(xpad1, wt1, d1, y1pad);
  // blur + noise + bias + lrelu + s2-scale -> out1pad
  blur_noise_act<<<1024, 256, 0, stream>>>(y1pad, n1, nw1, b1, s2, out1pad);
  // conv2 (XCD-swizzled) + fused ToRGB partials -> rgbpart (8 slabs, no atomics)
  gemm_conv2<<<1024, 256, 0, stream>>>(
      out1pad, wt2, d2, n2, nw2, b2, srgb, wrgb, rgbpart);
  // final: sum slabs + rgb bias + skip upsample
  rgb_finish<<<384, 256, 0, stream>>>(rgbpart, brgb, skip, (float*)d_out);
}

// Round 12
// 345.209 us; speedup vs baseline: 3.2341x; 1.0386x over previous
//
#include <hip/hip_runtime.h>
#include <stdint.h>

typedef unsigned short ushort_t;
typedef unsigned int uint_t;
typedef __bf16 bf16x8 __attribute__((ext_vector_type(8)));
typedef float f32x4 __attribute__((ext_vector_type(4)));

#define GLOBAL_AS __attribute__((address_space(1)))
#define LDS_AS    __attribute__((address_space(3)))

#define SCALE_CONV 0.014731391f   /* 1/sqrt(512*9) */
#define SCALE_RGB  0.044194174f   /* 1/sqrt(512)   */
#define SQRT2_F    1.41421356237f

// ---------------------------------------------------------------- helpers
__device__ __forceinline__ void async_cp16(const void* g, void* l) {
  __builtin_amdgcn_global_load_lds((const GLOBAL_AS uint_t*)g,
                                   (LDS_AS uint_t*)l, 16, 0, 0);
}
__device__ __forceinline__ ushort_t f2bf(float v) {
  union { float f; uint_t u; } c; c.f = v;
  uint_t r = c.u + 0x7fffu + ((c.u >> 16) & 1u);   // RNE
  return (ushort_t)(r >> 16);
}
__device__ __forceinline__ float bf2f(ushort_t u) {
  union { uint_t u; float f; } c; c.u = ((uint_t)u) << 16;
  return c.f;
}

// ------------------------------------------------- prep (merged): x->xpad1 and w1/w2->wt/wsqT
__global__ __launch_bounds__(256) void prep_all(
    const float* __restrict__ x, const float* __restrict__ s1,
    ushort_t* __restrict__ xpad,
    const float* __restrict__ w1, const float* __restrict__ w2,
    ushort_t* __restrict__ wt1, ushort_t* __restrict__ wt2,
    float* __restrict__ wsqT1, float* __restrict__ wsqT2) {
  if (blockIdx.x < 256) {
    __shared__ ushort_t t[32 * 520];
    const int b  = blockIdx.x >> 5;
    const int j1 = blockIdx.x & 31;
    for (int idx = threadIdx.x; idx < 512 * 32; idx += 256) {
      int ci = idx >> 5, j2 = idx & 31;
      float v = x[(size_t)(b * 512 + ci) * 1024 + j1 * 32 + j2];
      v *= s1[b * 512 + ci] * SCALE_CONV;
      t[j2 * 520 + ci] = f2bf(v);
    }
    __syncthreads();
    for (int idx = threadIdx.x; idx < 32 * 512; idx += 256) {
      int j2 = idx >> 9, ci = idx & 511;
      xpad[((size_t)(b * 34 + j1 + 1) * 34 + (j2 + 1)) * 512 + ci] = t[j2 * 520 + ci];
    }
    return;
  }
  int t = (blockIdx.x - 256) * 256 + threadIdx.x;   // 2*512*512
  const float* w  = (t < 262144) ? w1 : w2;
  ushort_t*   wt  = (t < 262144) ? wt1 : wt2;
  float*      wq  = (t < 262144) ? wsqT1 : wsqT2;
  int tt = t & 262143;
  int ci = tt & 511, co = tt >> 9;
  const float* wp = w + (size_t)(co * 512 + ci) * 9;
  float sq = 0.f;
#pragma unroll
  for (int u = 0; u < 9; ++u) {
    float v = wp[u];
    sq += v * v;
    wt[((size_t)u * 512 + co) * 512 + ci] = f2bf(v);
  }
  wq[ci * 512 + co] = sq;
}

// ------------------------------------------------- aux: demod (z=0,1) + pad-border zero (z=2..4)
__global__ __launch_bounds__(256) void aux_demod_border(
    const float* __restrict__ wsqT1, const float* __restrict__ s1, float* __restrict__ d1,
    const float* __restrict__ wsqT2, const float* __restrict__ s2, float* __restrict__ d2,
    ushort_t* __restrict__ xpad, ushort_t* __restrict__ ypad, ushort_t* __restrict__ opad) {
  const int z = blockIdx.z;
  if (z < 2) {
    if (blockIdx.x >= 8) return;
    const float* wq = z ? wsqT2 : wsqT1;
    const float* s  = z ? s2 : s1;
    float*       d  = z ? d2 : d1;
    const int b   = blockIdx.y;
    const int co  = blockIdx.x * 64 + (threadIdx.x & 63);
    const int cig = threadIdx.x >> 6;
    __shared__ float ssq[512];
    __shared__ float red[4][64];
    for (int i = threadIdx.x; i < 512; i += 256) {
      float v = s[b * 512 + i];
      ssq[i] = v * v;
    }
    __syncthreads();
    float a = 0.f;
#pragma unroll 4
    for (int ci = cig * 128; ci < cig * 128 + 128; ++ci)
      a += wq[ci * 512 + co] * ssq[ci];
    red[cig][threadIdx.x & 63] = a;
    __syncthreads();
    if (cig == 0) {
      int l = threadIdx.x & 63;
      float tot = red[0][l] + red[1][l] + red[2][l] + red[3][l];
      d[b * 512 + co] = rsqrtf(tot * (1.f / 4608.f) + 1e-8f);
    }
    return;
  }
  const int z2 = z - 2;
  ushort_t* p = (z2 == 0) ? xpad : (z2 == 1 ? ypad : opad);
  const int W = (z2 == 0) ? 34 : (z2 == 1 ? 67 : 66);
  const int nb = 4 * W - 4;
  const int t = blockIdx.x * 256 + threadIdx.x;
  const int pix = t >> 6, ch = (t & 63) * 8;
  if (pix >= nb) return;
  const int b = blockIdx.y;
  int y, x;
  if (pix < W)          { y = 0;     x = pix; }
  else if (pix < 2 * W) { y = W - 1; x = pix - W; }
  else { int q = pix - 2 * W; y = 1 + (q >> 1); x = (q & 1) ? W - 1 : 0; }
  uint4 z4 = {0, 0, 0, 0};
  *(uint4*)(p + ((size_t)(b * W + y) * W + x) * 512 + ch) = z4;
}

// ------------------------------------------------- conv1 phase tap tables (convT stride-2, k=3)
__constant__ int           c_ph_off[4]  = {0, 4, 6, 8};
__constant__ int           c_ph_ntap[4] = {4, 2, 2, 1};
__constant__ unsigned char c_tap_u1[9]  = {0,0,1,1, 0,1, 1,1, 1};
__constant__ unsigned char c_tap_u2[9]  = {0,1,0,1, 1,1, 0,1, 1};
__constant__ unsigned char c_tap_pl[9]  = {8,6,2,0, 7,1, 5,3, 4};

// ------------------------------------------------- conv1: unfused convT phase GEMM (BK=64)
// Longest-first grid: 288 ids per phase (phase 0 = 4 taps first, phase 3 = 1 tap last) so the
// 128 blocks beyond the 1024 co-resident are all 8-k-step ones (short tail). 288 % 8 == 0 keeps
// the XCD-colocate invariant: all (phase,ntile) blocks of one mtile have g == mtile (mod 8).
__global__ __launch_bounds__(256, 4) void gemm_conv1(
    const ushort_t* __restrict__ inp, const ushort_t* __restrict__ wt,
    const float* __restrict__ dmod, ushort_t* __restrict__ outp) {
  const int g = blockIdx.x;                 // 0..1151
  const int a = g / 288;                    // phase (ntap descending: 4,2,2,1)
  const int idp = g - a * 288;
  const int mg = idp >> 5;                  // 0..8
  const int ntile = (idp >> 3) & 3;
  const int mtile = mg * 8 + (idp & 7);
  if (mtile >= 69) return;
  const int a1 = a >> 1, a2 = a & 1;

  __shared__ ushort_t ldsA[128 * 64];
  __shared__ ushort_t ldsB[128 * 64];

  const int lane = threadIdx.x & 63;
  const int wv   = threadIdx.x >> 6;
  const int wm   = wv & 1;
  const int wn   = wv >> 1;
  const int l16  = lane & 15;
  const int quad = lane >> 4;

  const int cl = ((lane & 7) - (lane >> 3)) & 7;
  const char* pA[4];
  const char* pB[4];
#pragma unroll
  for (int t = 0; t < 4; ++t) {
    int row = wv * 32 + t * 8 + (lane >> 3);
    int m   = mtile * 128 + row;
    if (m > 8711) m = 8711;
    int b = m / 1089, rr = m % 1089;
    int p1 = rr / 33, p2 = rr % 33;
    size_t pix = ((size_t)(b * 34 + p1) * 34 + p2) * 512;
    pA[t] = (const char*)inp + pix * 2 + cl * 16;
    int n = ntile * 128 + row;
    pB[t] = (const char*)wt + (size_t)n * 1024 + cl * 16;
  }
  char* dstA[4];
  char* dstB[4];
#pragma unroll
  for (int t = 0; t < 4; ++t) {
    dstA[t] = (char*)ldsA + wv * 4096 + t * 1024;
    dstB[t] = (char*)ldsB + wv * 4096 + t * 1024;
  }

  int offA[4], offB[4];
#pragma unroll
  for (int i = 0; i < 4; ++i) {
    int r  = wm * 64 + i * 16 + l16;
    int rn = wn * 64 + i * 16 + l16;
    offA[i] = r  * 64 + (((quad + r)  & 7) << 3);
    offB[i] = rn * 64 + (((quad + rn) & 7) << 3);
  }

  f32x4 acc[4][4];
#pragma unroll
  for (int i = 0; i < 4; ++i)
#pragma unroll
    for (int j = 0; j < 4; ++j) acc[i][j] = (f32x4){0.f, 0.f, 0.f, 0.f};

  const int ntap = c_ph_ntap[a];
#pragma unroll 1
  for (int ti = 0; ti < ntap; ++ti) {
    int e = c_ph_off[a] + ti;
    int aoff = ((int)c_tap_u1[e] * 34 + (int)c_tap_u2[e]) * 1024;
    int boff = (int)c_tap_pl[e] * 524288;
#pragma unroll 1
    for (int kc = 0; kc < 8; ++kc) {
      const int koff = kc * 128;
      __syncthreads();
#pragma unroll
      for (int t = 0; t < 4; ++t) async_cp16(pA[t] + aoff + koff, dstA[t]);
#pragma unroll
      for (int t = 0; t < 4; ++t) async_cp16(pB[t] + boff + koff, dstB[t]);
      __syncthreads();
#pragma unroll
      for (int kk = 0; kk < 2; ++kk) {
        const int kx = kk << 5;
        bf16x8 af[4], bg[4];
#pragma unroll
        for (int i = 0; i < 4; ++i) af[i] = *reinterpret_cast<const bf16x8*>(ldsA + (offA[i] ^ kx));
#pragma unroll
        for (int j = 0; j < 4; ++j) bg[j] = *reinterpret_cast<const bf16x8*>(ldsB + (offB[j] ^ kx));
#pragma unroll
        for (int i = 0; i < 4; ++i)
#pragma unroll
          for (int j = 0; j < 4; ++j)
            acc[i][j] = __builtin_amdgcn_mfma_f32_16x16x32_bf16(af[i], bg[j], acc[i][j], 0, 0, 0);
      }
    }
  }

  int co_[4];
#pragma unroll
  for (int j = 0; j < 4; ++j) co_[j] = ntile * 128 + wn * 64 + j * 16 + l16;

#pragma unroll
  for (int i = 0; i < 4; ++i) {
#pragma unroll
    for (int r = 0; r < 4; ++r) {
      int m = mtile * 128 + wm * 64 + i * 16 + quad * 4 + r;
      if (m < 8712) {
        int b = m / 1089, rr = m % 1089;
        int p1 = rr / 33, p2 = rr % 33;
        if ((a1 == 0 || p1 < 32) && (a2 == 0 || p2 < 32)) {
          int o1 = 2 * p1 + a1, o2 = 2 * p2 + a2;
          size_t ob = ((size_t)(b * 67 + o1 + 1) * 67 + (o2 + 1)) * 512;
#pragma unroll
          for (int j = 0; j < 4; ++j)
            outp[ob + co_[j]] = f2bf(acc[i][j][r] * dmod[b * 512 + co_[j]]);
        }
      }
    }
  }
}

// ------------------------------------------------- conv2: R7 K-loop + fused ToRGB (no atomics)
__global__ __launch_bounds__(256, 3) void gemm_conv2(
    const ushort_t* __restrict__ inp, const ushort_t* __restrict__ wt,
    const float* __restrict__ dmod, const float* __restrict__ noise,
    const float* __restrict__ nw, const float* __restrict__ bias,
    const float* __restrict__ srgb, const float* __restrict__ wrgb,
    float* __restrict__ rgbpart) {
  const int g = blockIdx.x;
  const int mtile = ((g >> 5) << 3) | (g & 7);
  const int ntile = (g >> 3) & 3;

  __shared__ ushort_t ldsA[128 * 64];
  __shared__ ushort_t ldsB[128 * 64];

  const int lane = threadIdx.x & 63;
  const int wv   = threadIdx.x >> 6;
  const int wm   = wv & 1;
  const int wn   = wv >> 1;
  const int l16  = lane & 15;
  const int quad = lane >> 4;

  const int cl = ((lane & 7) - (lane >> 3)) & 7;
  const char* pA[4];
  const char* pB[4];
#pragma unroll
  for (int t = 0; t < 4; ++t) {
    int row = wv * 32 + t * 8 + (lane >> 3);
    int m   = mtile * 128 + row;
    int b = m >> 12, o1 = (m >> 6) & 63, o2 = m & 63;
    size_t pix = ((size_t)(b * 66 + o1 + 1) * 66 + (o2 + 1)) * 512;
    pA[t] = (const char*)inp + pix * 2 + cl * 16;
    int n = ntile * 128 + row;
    pB[t] = (const char*)wt + (size_t)n * 1024 + cl * 16;
  }
  char* dstA[4];
  char* dstB[4];
#pragma unroll
  for (int t = 0; t < 4; ++t) {
    dstA[t] = (char*)ldsA + wv * 4096 + t * 1024;
    dstB[t] = (char*)ldsB + wv * 4096 + t * 1024;
  }

  int offA[4], offB[4];
#pragma unroll
  for (int i = 0; i < 4; ++i) {
    int r  = wm * 64 + i * 16 + l16;
    int rn = wn * 64 + i * 16 + l16;
    offA[i] = r  * 64 + (((quad + r)  & 7) << 3);
    offB[i] = rn * 64 + (((quad + rn) & 7) << 3);
  }

  f32x4 acc[4][4];
#pragma unroll
  for (int i = 0; i < 4; ++i)
#pragma unroll
    for (int j = 0; j < 4; ++j) acc[i][j] = (f32x4){0.f, 0.f, 0.f, 0.f};

#pragma unroll 1
  for (int ti = 0; ti < 9; ++ti) {
    int aoff = ((ti / 3 - 1) * 66 + (ti % 3 - 1)) * 1024;
    int boff = ti * 524288;
#pragma unroll 1
    for (int kc = 0; kc < 8; ++kc) {
      const int koff = kc * 128;
      __syncthreads();
#pragma unroll
      for (int t = 0; t < 4; ++t) async_cp16(pA[t] + aoff + koff, dstA[t]);
#pragma unroll
      for (int t = 0; t < 4; ++t) async_cp16(pB[t] + boff + koff, dstB[t]);
      __syncthreads();
#pragma unroll
      for (int kk = 0; kk < 2; ++kk) {
        const int kx = kk << 5;
        bf16x8 af[4], bg[4];
#pragma unroll
        for (int i = 0; i < 4; ++i) af[i] = *reinterpret_cast<const bf16x8*>(ldsA + (offA[i] ^ kx));
#pragma unroll
        for (int j = 0; j < 4; ++j) bg[j] = *reinterpret_cast<const bf16x8*>(ldsB + (offB[j] ^ kx));
#pragma unroll
        for (int i = 0; i < 4; ++i)
#pragma unroll
          for (int j = 0; j < 4; ++j)
            acc[i][j] = __builtin_amdgcn_mfma_f32_16x16x32_bf16(af[i], bg[j], acc[i][j], 0, 0, 0);
      }
    }
  }

  // ---- epilogue: demod + noise + bias + lrelu*sqrt2 + srgb scale, then RGB projection
  const int b = mtile >> 5;
  int co_[4];
#pragma unroll
  for (int j = 0; j < 4; ++j) co_[j] = ntile * 128 + wn * 64 + j * 16 + l16;
  const float nwv = nw[0];
  float dj_[4], sj_[4], bj_[4], wr[3][4];
#pragma unroll
  for (int j = 0; j < 4; ++j) {
    dj_[j] = dmod[b * 512 + co_[j]];
    sj_[j] = srgb[b * 512 + co_[j]] * SCALE_RGB;
    bj_[j] = bias[co_[j]];
#pragma unroll
    for (int c = 0; c < 3; ++c) wr[c][j] = wrgb[c * 512 + co_[j]];
  }
  float* slab = rgbpart + (size_t)(ntile * 2 + wn) * 98304;
#pragma unroll
  for (int i = 0; i < 4; ++i) {
#pragma unroll
    for (int r = 0; r < 4; ++r) {
      int m = mtile * 128 + wm * 64 + i * 16 + quad * 4 + r;
      int o1 = (m >> 6) & 63, o2 = m & 63;
      float nz = nwv * noise[(b << 12) + (o1 << 6) + o2];
      float vv[4];
#pragma unroll
      for (int j = 0; j < 4; ++j) {
        float v = acc[i][j][r] * dj_[j] + nz + bj_[j];
        v = (v >= 0.f ? v : 0.2f * v) * SQRT2_F;
        vv[j] = v * sj_[j];
      }
#pragma unroll
      for (int c = 0; c < 3; ++c) {
        float s = vv[0] * wr[c][0] + vv[1] * wr[c][1] + vv[2] * wr[c][2] + vv[3] * wr[c][3];
        s += __shfl_xor(s, 1);
        s += __shfl_xor(s, 2);
        s += __shfl_xor(s, 4);
        s += __shfl_xor(s, 8);
        if (l16 == 0) slab[c * 32768 + m] = s;
      }
    }
  }
}

// ------------------------------------------------- blur v2: horizontal-then-vertical rolling
// thread = 4 ch (uint2) x 8 output cols x 2 output rows; 5 input rows x 11 cols = 55 loads per
// 16 outputs (amp 3.44 vs 5.5). Same weights, fp-equivalent association.
__global__ __launch_bounds__(256) void blur_noise_act(
    const ushort_t* __restrict__ y1pad, const float* __restrict__ noise,
    const float* __restrict__ nw, const float* __restrict__ bias,
    const float* __restrict__ s2, ushort_t* __restrict__ out1pad) {
  const int cq  = threadIdx.x & 127;          // channel quad: ch = cq*4
  const int pg  = blockIdx.x * 2 + (threadIdx.x >> 7);   // 0..2047
  const int b   = pg >> 8;
  const int q1  = ((pg >> 3) & 31) * 2;       // 2 output rows q1, q1+1
  const int q2g = (pg & 7) * 8;               // 8 output cols
  const float cw[4] = {0.25f, 0.75f, 0.75f, 0.25f};

  float acc[2][8][4];
#pragma unroll
  for (int j = 0; j < 2; ++j)
#pragma unroll
    for (int x = 0; x < 8; ++x)
#pragma unroll
      for (int e = 0; e < 4; ++e) acc[j][x][e] = 0.f;

#pragma unroll
  for (int r = 0; r < 5; ++r) {               // input rows q1+r
    float h[8][4];
#pragma unroll
    for (int x = 0; x < 8; ++x)
#pragma unroll
      for (int e = 0; e < 4; ++e) h[x][e] = 0.f;
    const ushort_t* rowp = y1pad + ((size_t)(b * 67 + q1 + r) * 67 + q2g) * 512 + cq * 4;
#pragma unroll
    for (int c = 0; c < 11; ++c) {
      ushort_t v[4];
      *(uint2*)v = *(const uint2*)(rowp + (size_t)c * 512);
      float f[4];
#pragma unroll
      for (int e = 0; e < 4; ++e) f[e] = bf2f(v[e]);
#pragma unroll
      for (int x = 0; x < 8; ++x) {
        int t = c - x;
        if (t >= 0 && t < 4) {
#pragma unroll
          for (int e = 0; e < 4; ++e) h[x][e] += cw[t] * f[e];
        }
      }
    }
#pragma unroll
    for (int j = 0; j < 2; ++j) {
      int t = r - j;
      if (t >= 0 && t < 4) {
#pragma unroll
        for (int x = 0; x < 8; ++x)
#pragma unroll
          for (int e = 0; e < 4; ++e) acc[j][x][e] += cw[t] * h[x][e];
      }
    }
  }

  const float nwv = nw[0];
  float bj[4], sj[4];
#pragma unroll
  for (int e = 0; e < 4; ++e) {
    bj[e] = bias[cq * 4 + e];
    sj[e] = s2[b * 512 + cq * 4 + e] * SCALE_CONV;
  }
#pragma unroll
  for (int j = 0; j < 2; ++j) {
#pragma unroll
    for (int x = 0; x < 8; ++x) {
      float nz = nwv * noise[(b << 12) + ((q1 + j) << 6) + (q2g + x)];
      ushort_t o[4];
#pragma unroll
      for (int e = 0; e < 4; ++e) {
        float v = acc[j][x][e] + nz + bj[e];
        v = (v >= 0.f ? v : 0.2f * v) * SQRT2_F * sj[e];
        o[e] = f2bf(v);
      }
      *(uint2*)(out1pad + ((size_t)(b * 66 + q1 + j + 1) * 66 + (q2g + x + 1)) * 512 + cq * 4) =
          *(uint2*)o;
    }
  }
}

// ------------------------------------------------- final: sum 8 rgb slabs + bias + skip upfirdn -> out
__global__ __launch_bounds__(256) void rgb_finish(
    const float* __restrict__ rgbpart, const float* __restrict__ brgb,
    const float* __restrict__ skip, float* __restrict__ out) {
  const int t = blockIdx.x * 256 + threadIdx.x;   // 3*32768
  if (t >= 98304) return;
  const int m = t & 32767, c = t >> 15;
  const int b = m >> 12, o1 = (m >> 6) & 63, o2 = m & 63;
  float v3 = 0.f;
#pragma unroll
  for (int p = 0; p < 8; ++p) v3 += rgbpart[(size_t)p * 98304 + t];
  int P1 = o1 >> 1, P2 = o2 >> 1;
  int jy0, jy1, jx0, jx1;
  float wy0, wy1, wx0, wx1;
  if ((o1 & 1) == 0) { jy0 = P1 - 1; wy0 = .25f; jy1 = P1;     wy1 = .75f; }
  else               { jy0 = P1;     wy0 = .75f; jy1 = P1 + 1; wy1 = .25f; }
  if ((o2 & 1) == 0) { jx0 = P2 - 1; wx0 = .25f; jx1 = P2;     wx1 = .75f; }
  else               { jx0 = P2;     wx0 = .75f; jx1 = P2 + 1; wx1 = .25f; }
  const float* sp = skip + (size_t)(b * 3 + c) * 1024;
  float sv = 0.f;
  if (jy0 >= 0 && jy0 < 32) {
    if (jx0 >= 0 && jx0 < 32) sv += wy0 * wx0 * sp[jy0 * 32 + jx0];
    if (jx1 >= 0 && jx1 < 32) sv += wy0 * wx1 * sp[jy0 * 32 + jx1];
  }
  if (jy1 >= 0 && jy1 < 32) {
    if (jx0 >= 0 && jx0 < 32) sv += wy1 * wx0 * sp[jy1 * 32 + jx0];
    if (jx1 >= 0 && jx1 < 32) sv += wy1 * wx1 * sp[jy1 * 32 + jx1];
  }
  out[((size_t)(b * 3 + c) << 12) + (o1 << 6) + o2] = v3 + brgb[c] + sv;
}

// ------------------------------------------------- launch
extern "C" void kernel_launch(void* const* d_in, const int* in_sizes, int n_in,
                              void* d_out, int out_size, void* d_ws, size_t ws_size,
                              hipStream_t stream) {
  const float* x    = (const float*)d_in[0];
  const float* skip = (const float*)d_in[1];
  const float* w1   = (const float*)d_in[2];
  const float* b1   = (const float*)d_in[3];
  const float* s1   = (const float*)d_in[4];
  const float* nw1  = (const float*)d_in[5];
  const float* n1   = (const float*)d_in[6];
  const float* w2   = (const float*)d_in[7];
  const float* b2   = (const float*)d_in[8];
  const float* s2   = (const float*)d_in[9];
  const float* nw2  = (const float*)d_in[10];
  const float* n2   = (const float*)d_in[11];
  const float* wrgb = (const float*)d_in[12];
  const float* brgb = (const float*)d_in[13];
  const float* srgb = (const float*)d_in[14];

  char* ws = (char*)d_ws;
  const size_t XPAD_B  = (size_t)8 * 34 * 34 * 512 * 2;   //  9,469,952
  const size_t Y1PAD_B = (size_t)8 * 67 * 67 * 512 * 2;   // 36,773,888
  const size_t OUT1_B  = (size_t)8 * 66 * 66 * 512 * 2;   // 35,684,352
  const size_t WT_B    = (size_t)9 * 512 * 512 * 2;       //  4,718,592
  size_t off = 0;
  ushort_t* xpad1   = (ushort_t*)(ws + off); off += XPAD_B;
  ushort_t* y1pad   = (ushort_t*)(ws + off); off += Y1PAD_B;
  ushort_t* out1pad = (ushort_t*)(ws + off); off += OUT1_B;
  ushort_t* wt1     = (ushort_t*)(ws + off); off += WT_B;
  ushort_t* wt2     = (ushort_t*)(ws + off); off += WT_B;
  float*    d1      = (float*)(ws + off);    off += 8 * 512 * 4;
  float*    d2      = (float*)(ws + off);    off += 8 * 512 * 4;
  float*    rgbpart = (float*)(ws + off);    off += (size_t)8 * 98304 * 4;  // 3 MB
  // wsqT1/2 alias y1pad (consumed by aux demod before borders/gemm touch y1pad)
  float*    wsqT1  = (float*)y1pad;
  float*    wsqT2  = wsqT1 + 512 * 512;

  prep_all<<<2304, 256, 0, stream>>>(x, s1, xpad1, w1, w2, wt1, wt2, wsqT1, wsqT2);
  // demod (z=0,1) + pad-border zero (z=2..4)
  aux_demod_border<<<dim3(66, 8, 5), 256, 0, stream>>>(
      wsqT1, s1, d1, wsqT2, s2, d2, xpad1, y1pad, out1pad);

  // conv1: unfused convT (4 phases, 9 taps total), longest-first + XCD-colocated -> y1pad
  gemm_conv1<<<1152, 256, 0, stream>>>(xpad1, wt1, d1, y1pad);
  // blur v2 + noise + bias + lrelu + s2-scale -> out1pad
  blur_noise_act<<<1024, 256, 0, stream>>>(y1pad, n1, nw1, b1, s2, out1pad);
  // conv2 (XCD-swizzled) + fused ToRGB partials -> rgbpart (8 slabs, no atomics)
  gemm_conv2<<<1024, 256, 0, stream>>>(
      out1pad, wt2, d2, n2, nw2, b2, srgb, wrgb, rgbpart);
  // final: sum slabs + rgb bias + skip upsample
  rgb_finish<<<384, 256, 0, stream>>>(rgbpart, brgb, skip, (float*)d_out);
}